// Round 1
// baseline (213.167 us; speedup 1.0000x reference)
//
#include <hip/hip_runtime.h>
#include <hip/hip_bf16.h>

#define HIDDEN 1024
#define NH 16
#define BATCH 2
#define SEQ 2048

typedef __attribute__((ext_vector_type(8))) short bf16x8;
typedef __attribute__((ext_vector_type(4))) float f32x4;

__device__ __forceinline__ ushort f2bf(float f) {
    __hip_bfloat16 h = __float2bfloat16(f);
    return *reinterpret_cast<ushort*>(&h);
}
__device__ __forceinline__ float fexp2(float x) {
#if __has_builtin(__builtin_amdgcn_exp2f)
    return __builtin_amdgcn_exp2f(x);
#else
    return exp2f(x);
#endif
}
// pack trunc-bf16(a) low, trunc-bf16(b) high (1 v_perm)
__device__ __forceinline__ uint pack_bf_trunc(float a, float b) {
    return __builtin_amdgcn_perm(__float_as_uint(b), __float_as_uint(a), 0x07060302u);
}

// async global->LDS, 16B per lane
__device__ __forceinline__ void async_copy16(const ushort* g, ushort* l) {
    __builtin_amdgcn_global_load_lds((const __attribute__((address_space(1))) void*)g,
                                     (__attribute__((address_space(3))) void*)l,
                                     16, 0, 0);
}

// ---------------------------------------------------------------------------
// Fused prep: [0,4096) x->bf16 | [4096,7168) Wqkv transpose | [7168,8192) Wo transpose
// ---------------------------------------------------------------------------
__global__ void prep_kernel(const float* __restrict__ x,
                            const float* __restrict__ Wqkv,
                            const float* __restrict__ Wo,
                            ushort* __restrict__ xb,
                            ushort* __restrict__ Wt,
                            ushort* __restrict__ WoT)
{
    __shared__ float t[32][33];
    const int bid = blockIdx.x;
    const int tid = threadIdx.x;

    if (bid < 4096) {
        int i = (bid * 256 + tid) * 4;
        float4 v = *(const float4*)(x + i);
        ushort4 w;
        w.x = f2bf(v.x); w.y = f2bf(v.y); w.z = f2bf(v.z); w.w = f2bf(v.w);
        *(ushort4*)(xb + i) = w;
        return;
    }
    const int r = tid >> 3;
    const int c = (tid & 7) * 4;
    if (bid < 7168) {
        int tt = bid - 4096;
        int k0 = (tt & 31) * 32;
        int n0 = (tt >> 5) * 32;
        const int N = 3 * HIDDEN, K = HIDDEN;
        float4 v = *(const float4*)(Wqkv + (size_t)(k0 + r) * N + n0 + c);
        t[r][c] = v.x; t[r][c + 1] = v.y; t[r][c + 2] = v.z; t[r][c + 3] = v.w;
        __syncthreads();
        ushort4 w;
        w.x = f2bf(t[c + 0][r]); w.y = f2bf(t[c + 1][r]);
        w.z = f2bf(t[c + 2][r]); w.w = f2bf(t[c + 3][r]);
        *(ushort4*)(Wt + (size_t)(n0 + r) * K + k0 + c) = w;
    } else {
        int tt = bid - 7168;
        int k0 = (tt & 31) * 32;
        int n0 = (tt >> 5) * 32;
        const int N = HIDDEN, K = HIDDEN;
        float4 v = *(const float4*)(Wo + (size_t)(k0 + r) * N + n0 + c);
        t[r][c] = v.x; t[r][c + 1] = v.y; t[r][c + 2] = v.z; t[r][c + 3] = v.w;
        __syncthreads();
        ushort4 w;
        w.x = f2bf(t[c + 0][r]); w.y = f2bf(t[c + 1][r]);
        w.z = f2bf(t[c + 2][r]); w.w = f2bf(t[c + 3][r]);
        *(ushort4*)(WoT + (size_t)(n0 + r) * K + k0 + c) = w;
    }
}

// ---------------------------------------------------------------------------
// bf16 MFMA GEMM1: qkv = x @ Wqkv^T + bias -> bf16. Q cols scaled by qscale
// (0.125*log2e -> softmax via exp2). When vt_mode, V cols (>=2048) go
// transposed + Pi-permuted into vtg[b][h][d][s'] (fused transpose_v).
// ---------------------------------------------------------------------------
__global__ __launch_bounds__(256, 3)
void gemm_mfma_bf16_kernel(const ushort* __restrict__ A,
                           const ushort* __restrict__ Bt,
                           const float* __restrict__ bias,
                           ushort* __restrict__ C, int N,
                           int qscale_cols, float qscale,
                           ushort* __restrict__ vtg, int vt_mode)
{
    constexpr int K = 1024;
    __shared__ ushort As[128 * 64];
    __shared__ ushort Bs[128 * 64];

    const int tid  = threadIdx.x;
    const int wave = tid >> 6;
    const int lane = tid & 63;
    const int l16  = lane & 15;
    const int quad = lane >> 4;
    const int wm = wave & 1, wn = wave >> 1;

    const int bm = blockIdx.y * 128;
    const int bn = blockIdx.x * 128;

    const int srow = lane >> 3;
    const int lblk = (lane & 7) ^ srow;
    const ushort* Ag = A  + (size_t)(bm + wave * 32 + srow) * K + lblk * 8;
    const ushort* Bg = Bt + (size_t)(bn + wave * 32 + srow) * K + lblk * 8;
    ushort* Asl = As + wave * 32 * 64;
    ushort* Bsl = Bs + wave * 32 * 64;

    f32x4 acc[4][4];
    #pragma unroll
    for (int i = 0; i < 4; i++)
        #pragma unroll
        for (int j = 0; j < 4; j++) acc[i][j] = (f32x4){0.f, 0.f, 0.f, 0.f};

    for (int k0 = 0; k0 < K; k0 += 64) {
        __syncthreads();
        #pragma unroll
        for (int t = 0; t < 4; t++) {
            async_copy16(Ag + (size_t)t * 8 * K + k0, Asl + t * 8 * 64);
            async_copy16(Bg + (size_t)t * 8 * K + k0, Bsl + t * 8 * 64);
        }
        __syncthreads();

        #pragma unroll
        for (int s = 0; s < 2; s++) {
            bf16x8 af[4], bfr[4];
            #pragma unroll
            for (int i = 0; i < 4; i++) {
                int m = wm * 64 + i * 16 + l16;
                int n = wn * 64 + i * 16 + l16;
                af[i]  = *(const bf16x8*)&As[m * 64 + (((s * 4 + quad) ^ (m & 7)) << 3)];
                bfr[i] = *(const bf16x8*)&Bs[n * 64 + (((s * 4 + quad) ^ (n & 7)) << 3)];
            }
            #pragma unroll
            for (int i = 0; i < 4; i++)
                #pragma unroll
                for (int j = 0; j < 4; j++)
                    acc[i][j] = __builtin_amdgcn_mfma_f32_16x16x32_bf16(af[i], bfr[j], acc[i][j], 0, 0, 0);
        }
    }

    #pragma unroll
    for (int j = 0; j < 4; j++) {
        int col = bn + wn * 64 + j * 16 + l16;
        float bv = bias[col];
        if (vt_mode && col >= 2048) {
            // V -> vtg transposed + Pi: s64 = i*16+quad*4+r; Pi(s64)=(quad*4+r)*4+i
            int dfull = col - 2048;
            int hh = dfull >> 6, dd = dfull & 63;
            int bb = bm >> 11;
            int sb = ((bm & 2047) + wm * 64) >> 6;
            ushort tmp[16];
            #pragma unroll
            for (int i = 0; i < 4; i++)
                #pragma unroll
                for (int r = 0; r < 4; r++)
                    tmp[r * 4 + i] = f2bf(acc[i][j][r] + bv);
            ushort* dst = vtg + ((size_t)((bb * NH + hh) * 64 + dd)) * SEQ
                          + sb * 64 + quad * 16;
            *(uint4*)dst = *(const uint4*)tmp;
            *(uint4*)(dst + 8) = *(const uint4*)(tmp + 8);
        } else {
            float s = (col < qscale_cols) ? qscale : 1.0f;
            #pragma unroll
            for (int i = 0; i < 4; i++) {
                int row0 = bm + wm * 64 + i * 16 + quad * 4;
                #pragma unroll
                for (int r = 0; r < 4; r++)
                    C[(size_t)(row0 + r) * N + col] = f2bf((acc[i][j][r] + bv) * s);
            }
        }
    }
}

// ---------------------------------------------------------------------------
// Output projection, single-pass bf16 MFMA: C[4096][1024]f32 = attn @ WoT^T + bo.
// Tile 128(M)x64(N), BK=64, grid 512 (2+/CU), LDS 24 KB.
// ---------------------------------------------------------------------------
__global__ __launch_bounds__(256, 4)
void gemm_out_kernel(const ushort* __restrict__ A,
                     const ushort* __restrict__ Bt,
                     const float* __restrict__ bias,
                     float* __restrict__ C)
{
    constexpr int K = 1024, N = 1024;
    __shared__ ushort As[128 * 64];
    __shared__ ushort Bs[64 * 64];

    const int tid  = threadIdx.x;
    const int wave = tid >> 6;
    const int lane = tid & 63;
    const int l16  = lane & 15;
    const int quad = lane >> 4;
    const int wm = wave & 1, wn = wave >> 1;

    const int bm = blockIdx.y * 128;
    const int bn = blockIdx.x * 64;

    const int srow = lane >> 3;
    const int lblk = (lane & 7) ^ srow;
    const ushort* Ag = A  + (size_t)(bm + wave * 32 + srow) * K + lblk * 8;
    const ushort* Bg = Bt + (size_t)(bn + wave * 16 + srow) * K + lblk * 8;
    ushort* Asl = As + wave * 32 * 64;
    ushort* Bsl = Bs + wave * 16 * 64;

    f32x4 acc[4][2];
    #pragma unroll
    for (int i = 0; i < 4; i++)
        #pragma unroll
        for (int j = 0; j < 2; j++) acc[i][j] = (f32x4){0.f, 0.f, 0.f, 0.f};

    for (int k0 = 0; k0 < K; k0 += 64) {
        __syncthreads();
        #pragma unroll
        for (int t = 0; t < 4; t++)
            async_copy16(Ag + (size_t)t * 8 * K + k0, Asl + t * 8 * 64);
        #pragma unroll
        for (int t = 0; t < 2; t++)
            async_copy16(Bg + (size_t)t * 8 * K + k0, Bsl + t * 8 * 64);
        __syncthreads();

        #pragma unroll
        for (int s = 0; s < 2; s++) {
            bf16x8 af[4], bfr[2];
            #pragma unroll
            for (int i = 0; i < 4; i++) {
                int m = wm * 64 + i * 16 + l16;
                af[i] = *(const bf16x8*)&As[m * 64 + (((s * 4 + quad) ^ (m & 7)) << 3)];
            }
            #pragma unroll
            for (int j = 0; j < 2; j++) {
                int n = wn * 32 + j * 16 + l16;
                bfr[j] = *(const bf16x8*)&Bs[n * 64 + (((s * 4 + quad) ^ (n & 7)) << 3)];
            }
            #pragma unroll
            for (int i = 0; i < 4; i++)
                #pragma unroll
                for (int j = 0; j < 2; j++)
                    acc[i][j] = __builtin_amdgcn_mfma_f32_16x16x32_bf16(af[i], bfr[j], acc[i][j], 0, 0, 0);
        }
    }

    #pragma unroll
    for (int j = 0; j < 2; j++) {
        int col = bn + wn * 32 + j * 16 + l16;
        float bv = bias[col];
        #pragma unroll
        for (int i = 0; i < 4; i++) {
            int row0 = bm + wm * 64 + i * 16 + quad * 4;
            #pragma unroll
            for (int r = 0; r < 4; r++)
                C[(size_t)(row0 + r) * N + col] = acc[i][j][r] + bv;
        }
    }
}

// ---------------------------------------------------------------------------
// Flash attention v7: v6 structure + (a) T14 reg-prefetch of next K/V tile
// (issue global_load_dwordx4 at iter top; vmcnt-drain + ds_write after the
// post-PV barrier -> global latency hidden under QK/softmax/PV), and
// (b) XCD-bijective block swizzle: all 16 qb-blocks of one (b,h) land on one
// XCD (64 blocks/XCD = 32 CU x 2 blocks), so K/V (512 KB/head, 4 heads = 2 MB)
// stays resident in that XCD's 4 MB L2. LDS unchanged (69.6 KB, 2 blocks/CU).
// ---------------------------------------------------------------------------
__global__ __launch_bounds__(256, 2)
void attn_mfma_v7_kernel(const ushort* __restrict__ qkvb,
                         const ushort* __restrict__ vtg,
                         ushort* __restrict__ attn)
{
    // ushort layout: Ks[2][4096] | Vs[2][4096] @8192 | Ps[4][4608] @16384
    __shared__ __align__(16) ushort smem[34816];

    const int tid  = threadIdx.x;
    const int wave = tid >> 6;
    const int qg   = wave & 1;
    const int kh   = wave >> 1;
    const int lane = tid & 63;
    const int l16  = lane & 15;
    const int quad = lane >> 4;

    // XCD swizzle: xcd = bid&7 gets heads [xcd*4, xcd*4+4), all 16 qb each.
    const int obid = blockIdx.x;
    const int qb = (obid >> 3) & 15;
    const int bh = (obid & 7) * 4 + (obid >> 7);
    const int h  = bh & (NH - 1);
    const int b  = bh >> 4;

    const int qbase = qb * 128 + qg * 64;
    const int hoff  = h * 64;

    ushort* KsH = smem + kh * 4096;
    ushort* VsH = smem + 8192 + kh * 4096;
    ushort* Psw = smem + 16384 + wave * 4608;

    bf16x8 a_q[4][2];
    #pragma unroll
    for (int mg = 0; mg < 4; mg++) {
        int qrow = b * SEQ + qbase + mg * 16 + l16;
        const ushort* qp = qkvb + (size_t)qrow * 3072 + hoff + quad * 8;
        a_q[mg][0] = *(const bf16x8*)qp;
        a_q[mg][1] = *(const bf16x8*)(qp + 32);
    }

    f32x4 o[4][4];
    f32x4 lacc[4];
    #pragma unroll
    for (int mg = 0; mg < 4; mg++) {
        lacc[mg] = (f32x4){0.f, 0.f, 0.f, 0.f};
        #pragma unroll
        for (int nt = 0; nt < 4; nt++) o[mg][nt] = (f32x4){0.f, 0.f, 0.f, 0.f};
    }

    bf16x8 b_ones;
    #pragma unroll
    for (int j = 0; j < 8; j++) b_ones[j] = (short)0x3f80;

    const ushort* kvb    = qkvb + (size_t)b * SEQ * 3072;
    const ushort* vtg_bh = vtg + (size_t)((b * NH + h) * 64) * SEQ;

    const int srow8 = lane >> 3;
    const int gblk  = ((lane & 7) ^ srow8) << 3;
    const ushort* kg = kvb + (size_t)(kh * 1024 + qg * 32 + srow8) * 3072 + 1024 + hoff + gblk;
    const ushort* vg = vtg_bh + (size_t)(qg * 32 + srow8) * SEQ + kh * 1024 + gblk;

    // prologue: stage tile 0 directly to LDS (async), drain at the barrier
    #pragma unroll
    for (int c = 0; c < 4; c++) {
        async_copy16(kg + (size_t)(c * 8) * 3072, KsH + (qg * 32 + c * 8) * 64);
        async_copy16(vg + (size_t)(c * 8) * SEQ,  VsH + (qg * 32 + c * 8) * 64);
    }
    __syncthreads();

    uint4 kpre[4], vpre[4];

    for (int t = 0; t < 16; t++) {
        // T14 issue-early: prefetch tile t+1 into regs; consumed after the
        // post-PV barrier, so ~full HBM/L2 latency hides under compute.
        if (t < 15) {
            const int k0n = (t + 1) * 64;
            #pragma unroll
            for (int c = 0; c < 4; c++) {
                kpre[c] = *(const uint4*)(kg + (size_t)(k0n + c * 8) * 3072);
                vpre[c] = *(const uint4*)(vg + (size_t)(c * 8) * SEQ + k0n);
            }
        }

        f32x4 sc[4][4];
        #pragma unroll
        for (int nt = 0; nt < 4; nt++) {
            int key = nt * 16 + l16;
            bf16x8 bk0 = *(const bf16x8*)&KsH[key * 64 + ((quad ^ (key & 7)) << 3)];
            bf16x8 bk1 = *(const bf16x8*)&KsH[key * 64 + (((4 + quad) ^ (key & 7)) << 3)];
            #pragma unroll
            for (int mg = 0; mg < 4; mg++) {
                f32x4 a = (f32x4){0.f, 0.f, 0.f, 0.f};
                a = __builtin_amdgcn_mfma_f32_16x16x32_bf16(a_q[mg][0], bk0, a, 0, 0, 0);
                a = __builtin_amdgcn_mfma_f32_16x16x32_bf16(a_q[mg][1], bk1, a, 0, 0, 0);
                sc[mg][nt] = a;
            }
        }

        #pragma unroll
        for (int mg = 0; mg < 4; mg++) {
            #pragma unroll
            for (int r = 0; r < 4; r++) {
                int q = mg * 16 + quad * 4 + r;
                uint2 pk2;
                pk2.x = pack_bf_trunc(fexp2(sc[mg][0][r]), fexp2(sc[mg][1][r]));
                pk2.y = pack_bf_trunc(fexp2(sc[mg][2][r]), fexp2(sc[mg][3][r]));
                *(uint2*)&Psw[q * 72 + l16 * 4] = pk2;
            }
        }

        asm volatile("s_waitcnt lgkmcnt(0)" ::: "memory");

        #pragma unroll
        for (int mg = 0; mg < 4; mg++) {
            bf16x8 ap0 = *(const bf16x8*)&Psw[(mg * 16 + l16) * 72 + quad * 8];
            bf16x8 ap1 = *(const bf16x8*)&Psw[(mg * 16 + l16) * 72 + 32 + quad * 8];
            #pragma unroll
            for (int nt = 0; nt < 4; nt++) {
                int d = nt * 16 + l16;
                bf16x8 bv0 = *(const bf16x8*)&VsH[d * 64 + ((quad ^ (d & 7)) << 3)];
                bf16x8 bv1 = *(const bf16x8*)&VsH[d * 64 + (((4 + quad) ^ (d & 7)) << 3)];
                o[mg][nt] = __builtin_amdgcn_mfma_f32_16x16x32_bf16(ap0, bv0, o[mg][nt], 0, 0, 0);
                o[mg][nt] = __builtin_amdgcn_mfma_f32_16x16x32_bf16(ap1, bv1, o[mg][nt], 0, 0, 0);
            }
            lacc[mg] = __builtin_amdgcn_mfma_f32_16x16x32_bf16(ap0, b_ones, lacc[mg], 0, 0, 0);
            lacc[mg] = __builtin_amdgcn_mfma_f32_16x16x32_bf16(ap1, b_ones, lacc[mg], 0, 0, 0);
        }

        // all waves done reading tile t, then write-late the prefetched tile
        __syncthreads();
        if (t < 15) {
            #pragma unroll
            for (int c = 0; c < 4; c++) {
                *(uint4*)(KsH + (qg * 32 + c * 8) * 64 + lane * 8) = kpre[c];
                *(uint4*)(VsH + (qg * 32 + c * 8) * 64 + lane * 8) = vpre[c];
            }
            __syncthreads();
        }
    }

    // combine key-halves
    __syncthreads();
    float* osc = (float*)smem;
    float* lsc = (float*)(smem + 16384);
    const int ob = qg * 4096;
    const int lb = qg * 64;
    if (kh == 1) {
        #pragma unroll
        for (int mg = 0; mg < 4; mg++) {
            #pragma unroll
            for (int nt = 0; nt < 4; nt++)
                *(f32x4*)&osc[ob + ((mg * 4 + nt) * 4 + quad) * 64 + l16 * 4] = o[mg][nt];
            if (l16 == 0) *(f32x4*)&lsc[lb + (mg * 4 + quad) * 4] = lacc[mg];
        }
    }
    __syncthreads();
    if (kh == 0) {
        #pragma unroll
        for (int mg = 0; mg < 4; mg++) {
            #pragma unroll
            for (int nt = 0; nt < 4; nt++)
                o[mg][nt] += *(const f32x4*)&osc[ob + ((mg * 4 + nt) * 4 + quad) * 64 + l16 * 4];
            lacc[mg] += *(const f32x4*)&lsc[lb + (mg * 4 + quad) * 4];
        }
        #pragma unroll
        for (int mg = 0; mg < 4; mg++) {
            #pragma unroll
            for (int r = 0; r < 4; r++) {
                float inv = 1.f / lacc[mg][r];
                int row = b * SEQ + qbase + mg * 16 + quad * 4 + r;
                size_t base = (size_t)row * HIDDEN + hoff + l16;
                #pragma unroll
                for (int nt = 0; nt < 4; nt++)
                    attn[base + nt * 16] = f2bf(o[mg][nt][r] * inv);
            }
        }
    }
}

// ---------------------------------------------------------------------------
// Fallback attention (no vtg workspace): barrier kernel staging K + Pi-V.
// ---------------------------------------------------------------------------
__global__ __launch_bounds__(512, 4)
void attn_mfma_fb_kernel(const ushort* __restrict__ qkvb,
                         ushort* __restrict__ attn)
{
    __shared__ __align__(16) ushort smem[34816];

    const int tid   = threadIdx.x;
    const int wave  = tid >> 6;
    const int wavel = wave & 3;
    const int kh    = wave >> 2;
    const int lane  = tid & 63;
    const int l16   = lane & 15;
    const int quad  = lane >> 4;

    const int qb = blockIdx.x & 15;
    const int bh = blockIdx.x >> 4;
    const int h  = bh & (NH - 1);
    const int b  = bh >> 4;

    const int qbase = qb * 128;
    const int hoff  = h * 64;

    ushort* KsH = smem + kh * 4096;
    ushort* VsH = smem + 8192 + kh * 4096;
    ushort* Psw = smem + 16384 + wave * 2304;

    bf16x8 a_q[2][2];
    #pragma unroll
    for (int mg = 0; mg < 2; mg++) {
        int qrow = b * SEQ + qbase + wavel * 32 + mg * 16 + l16;
        const ushort* qp = qkvb + (size_t)qrow * 3072 + hoff + quad * 8;
        a_q[mg][0] = *(const bf16x8*)qp;
        a_q[mg][1] = *(const bf16x8*)(qp + 32);
    }

    f32x4 o[2][4];
    f32x4 lacc[2];
    #pragma unroll
    for (int mg = 0; mg < 2; mg++) {
        lacc[mg] = (f32x4){0.f, 0.f, 0.f, 0.f};
        #pragma unroll
        for (int nt = 0; nt < 4; nt++) o[mg][nt] = (f32x4){0.f, 0.f, 0.f, 0.f};
    }

    bf16x8 b_ones;
    #pragma unroll
    for (int j = 0; j < 8; j++) b_ones[j] = (short)0x3f80;

    const ushort* kvb = qkvb + (size_t)b * SEQ * 3072;

    for (int t = 0; t < 16; t++) {
        const int k0 = t * 64;
        __syncthreads();
        {
            const int tl = tid & 255;
            #pragma unroll
            for (int i = 0; i < 2; i++) {
                int key = (tl >> 3) + 32 * i;
                int blk = tl & 7;
                const ushort* ksrc = kvb + (size_t)(kh * 1024 + k0 + key) * 3072 + 1024 + hoff + blk * 8;
                uint4 kv = *(const uint4*)ksrc;
                *(uint4*)&KsH[key * 64 + ((blk ^ (key & 7)) << 3)] = kv;
                uint4 vv = *(const uint4*)(ksrc + 1024);
                const ushort* vpp = (const ushort*)&vv;
                int pk_ = (key & 15) * 4 + (key >> 4);
                #pragma unroll
                for (int j = 0; j < 8; j++) {
                    int d = blk * 8 + j;
                    VsH[d * 64 + (((pk_ >> 3) ^ (d & 7)) << 3) + (pk_ & 7)] = vpp[j];
                }
            }
        }
        __syncthreads();

        f32x4 sc[2][4];
        #pragma unroll
        for (int nt = 0; nt < 4; nt++) {
            int key = nt * 16 + l16;
            bf16x8 bk0 = *(const bf16x8*)&KsH[key * 64 + ((quad ^ (key & 7)) << 3)];
            bf16x8 bk1 = *(const bf16x8*)&KsH[key * 64 + (((4 + quad) ^ (key & 7)) << 3)];
            #pragma unroll
            for (int mg = 0; mg < 2; mg++) {
                f32x4 a = (f32x4){0.f, 0.f, 0.f, 0.f};
                a = __builtin_amdgcn_mfma_f32_16x16x32_bf16(a_q[mg][0], bk0, a, 0, 0, 0);
                a = __builtin_amdgcn_mfma_f32_16x16x32_bf16(a_q[mg][1], bk1, a, 0, 0, 0);
                sc[mg][nt] = a;
            }
        }

        #pragma unroll
        for (int mg = 0; mg < 2; mg++) {
            #pragma unroll
            for (int r = 0; r < 4; r++) {
                int q = mg * 16 + quad * 4 + r;
                uint2 pk2;
                pk2.x = pack_bf_trunc(fexp2(sc[mg][0][r]), fexp2(sc[mg][1][r]));
                pk2.y = pack_bf_trunc(fexp2(sc[mg][2][r]), fexp2(sc[mg][3][r]));
                *(uint2*)&Psw[q * 72 + l16 * 4] = pk2;
            }
        }

        asm volatile("s_waitcnt lgkmcnt(0)" ::: "memory");
        bf16x8 a_p[2][2];
        #pragma unroll
        for (int mg = 0; mg < 2; mg++) {
            a_p[mg][0] = *(const bf16x8*)&Psw[(mg * 16 + l16) * 72 + quad * 8];
            a_p[mg][1] = *(const bf16x8*)&Psw[(mg * 16 + l16) * 72 + 32 + quad * 8];
        }

        #pragma unroll
        for (int nt = 0; nt < 4; nt++) {
            int d = nt * 16 + l16;
            bf16x8 bv0 = *(const bf16x8*)&VsH[d * 64 + ((quad ^ (d & 7)) << 3)];
            bf16x8 bv1 = *(const bf16x8*)&VsH[d * 64 + (((4 + quad) ^ (d & 7)) << 3)];
            #pragma unroll
            for (int mg = 0; mg < 2; mg++) {
                o[mg][nt] = __builtin_amdgcn_mfma_f32_16x16x32_bf16(a_p[mg][0], bv0, o[mg][nt], 0, 0, 0);
                o[mg][nt] = __builtin_amdgcn_mfma_f32_16x16x32_bf16(a_p[mg][1], bv1, o[mg][nt], 0, 0, 0);
            }
        }
        #pragma unroll
        for (int mg = 0; mg < 2; mg++) {
            lacc[mg] = __builtin_amdgcn_mfma_f32_16x16x32_bf16(a_p[mg][0], b_ones, lacc[mg], 0, 0, 0);
            lacc[mg] = __builtin_amdgcn_mfma_f32_16x16x32_bf16(a_p[mg][1], b_ones, lacc[mg], 0, 0, 0);
        }
    }

    __syncthreads();
    float* osc = (float*)smem;
    float* lsc = (float*)(smem + 16384);
    const int fo = wavel * 2048 + quad * 64 + l16 * 4;
    const int fl = wavel * 512 + quad * 64 + l16 * 4;
    if (kh == 1) {
        #pragma unroll
        for (int mg = 0; mg < 2; mg++) {
            #pragma unroll
            for (int nt = 0; nt < 4; nt++)
                *(f32x4*)&osc[fo + (mg * 4 + nt) * 256] = o[mg][nt];
            *(f32x4*)&lsc[fl + mg * 256] = lacc[mg];
        }
    }
    __syncthreads();
    if (kh == 0) {
        #pragma unroll
        for (int mg = 0; mg < 2; mg++) {
            #pragma unroll
            for (int nt = 0; nt < 4; nt++)
                o[mg][nt] += *(const f32x4*)&osc[fo + (mg * 4 + nt) * 256];
            lacc[mg] += *(const f32x4*)&lsc[fl + mg * 256];
        }
        #pragma unroll
        for (int mg = 0; mg < 2; mg++) {
            #pragma unroll
            for (int r = 0; r < 4; r++) {
                float inv = 1.f / lacc[mg][r];
                int row = b * SEQ + qbase + wavel * 32 + mg * 16 + quad * 4 + r;
                size_t base = (size_t)row * HIDDEN + hoff + l16;
                #pragma unroll
                for (int nt = 0; nt < 4; nt++)
                    attn[base + nt * 16] = f2bf(o[mg][nt][r] * inv);
            }
        }
    }
}

extern "C" void kernel_launch(void* const* d_in, const int* in_sizes, int n_in,
                              void* d_out, int out_size, void* d_ws, size_t ws_size,
                              hipStream_t stream) {
    const float* x    = (const float*)d_in[0];
    const float* Wqkv = (const float*)d_in[1];
    const float* bqkv = (const float*)d_in[2];
    const float* Wo   = (const float*)d_in[3];
    const float* bo   = (const float*)d_in[4];
    float* out = (float*)d_out;

    const int M = BATCH * SEQ;                   // 4096
    const size_t MB = 1024 * 1024;

    // workspace (48 MB):
    //   [0,24) qkvb | [24,32) attn (xb overlaps: prep/GEMM1 only)
    //   [32,38) Wt (prep/GEMM1) | [38,40) WoT (prep->GEMM3) | [40,48) vtg
    char* ws = (char*)d_ws;
    ushort* qkvb = (ushort*)ws;
    ushort* attn = (ushort*)(ws + 24 * MB);
    ushort* xb   = (ushort*)(ws + 24 * MB);
    ushort* Wt   = (ushort*)(ws + 32 * MB);
    ushort* WoT  = (ushort*)(ws + 38 * MB);
    ushort* vtg  = (ushort*)(ws + 40 * MB);
    const int use_vtg = (ws_size >= 48 * MB) ? 1 : 0;

    const float qscale = 0.125f * 1.44269504088896f;   // fold log2e -> exp2 softmax

    // 0) fused preps (x->bf16, Wqkv transpose, Wo transpose)
    prep_kernel<<<8192, 256, 0, stream>>>(x, Wqkv, Wo, xb, Wt, WoT);

    // 1) qkv = (x @ Wqkv + bqkv) -> bf16; V written transposed to vtg when able
    {
        dim3 grid((3 * HIDDEN) / 128, M / 128);
        gemm_mfma_bf16_kernel<<<grid, 256, 0, stream>>>(xb, Wt, bqkv, qkvb,
                                                        3 * HIDDEN, HIDDEN, qscale,
                                                        vtg, use_vtg);
    }

    // 2) flash attention -> attn bf16
    if (use_vtg) {
        attn_mfma_v7_kernel<<<BATCH * NH * (SEQ / 128), 256, 0, stream>>>(
            qkvb, vtg, attn);
    } else {
        attn_mfma_fb_kernel<<<BATCH * NH * (SEQ / 128), 512, 0, stream>>>(
            qkvb, attn);
    }

    // 3) out = attn @ Wo + bo (single-pass bf16 MFMA)
    {
        dim3 grid(HIDDEN / 64, M / 128);
        gemm_out_kernel<<<grid, 256, 0, stream>>>(attn, WoT, bo, out);
    }
}

// Round 2
// 181.012 us; speedup vs baseline: 1.1776x; 1.1776x over previous
//
#include <hip/hip_runtime.h>
#include <hip/hip_bf16.h>

#define HIDDEN 1024
#define NH 16
#define BATCH 2
#define SEQ 2048

typedef __attribute__((ext_vector_type(8))) short bf16x8;
typedef __attribute__((ext_vector_type(4))) float f32x4;

__device__ __forceinline__ ushort f2bf(float f) {
    __hip_bfloat16 h = __float2bfloat16(f);
    return *reinterpret_cast<ushort*>(&h);
}
__device__ __forceinline__ float fexp2(float x) {
#if __has_builtin(__builtin_amdgcn_exp2f)
    return __builtin_amdgcn_exp2f(x);
#else
    return exp2f(x);
#endif
}
// pack trunc-bf16(a) low, trunc-bf16(b) high (1 v_perm)
__device__ __forceinline__ uint pack_bf_trunc(float a, float b) {
    return __builtin_amdgcn_perm(__float_as_uint(b), __float_as_uint(a), 0x07060302u);
}

// async global->LDS, 16B per lane
__device__ __forceinline__ void async_copy16(const ushort* g, ushort* l) {
    __builtin_amdgcn_global_load_lds((const __attribute__((address_space(1))) void*)g,
                                     (__attribute__((address_space(3))) void*)l,
                                     16, 0, 0);
}

// ---------------------------------------------------------------------------
// Fused prep: [0,4096) x->bf16 | [4096,7168) Wqkv transpose | [7168,8192) Wo transpose
// ---------------------------------------------------------------------------
__global__ void prep_kernel(const float* __restrict__ x,
                            const float* __restrict__ Wqkv,
                            const float* __restrict__ Wo,
                            ushort* __restrict__ xb,
                            ushort* __restrict__ Wt,
                            ushort* __restrict__ WoT)
{
    __shared__ float t[32][33];
    const int bid = blockIdx.x;
    const int tid = threadIdx.x;

    if (bid < 4096) {
        int i = (bid * 256 + tid) * 4;
        float4 v = *(const float4*)(x + i);
        ushort4 w;
        w.x = f2bf(v.x); w.y = f2bf(v.y); w.z = f2bf(v.z); w.w = f2bf(v.w);
        *(ushort4*)(xb + i) = w;
        return;
    }
    const int r = tid >> 3;
    const int c = (tid & 7) * 4;
    if (bid < 7168) {
        int tt = bid - 4096;
        int k0 = (tt & 31) * 32;
        int n0 = (tt >> 5) * 32;
        const int N = 3 * HIDDEN, K = HIDDEN;
        float4 v = *(const float4*)(Wqkv + (size_t)(k0 + r) * N + n0 + c);
        t[r][c] = v.x; t[r][c + 1] = v.y; t[r][c + 2] = v.z; t[r][c + 3] = v.w;
        __syncthreads();
        ushort4 w;
        w.x = f2bf(t[c + 0][r]); w.y = f2bf(t[c + 1][r]);
        w.z = f2bf(t[c + 2][r]); w.w = f2bf(t[c + 3][r]);
        *(ushort4*)(Wt + (size_t)(n0 + r) * K + k0 + c) = w;
    } else {
        int tt = bid - 7168;
        int k0 = (tt & 31) * 32;
        int n0 = (tt >> 5) * 32;
        const int N = HIDDEN, K = HIDDEN;
        float4 v = *(const float4*)(Wo + (size_t)(k0 + r) * N + n0 + c);
        t[r][c] = v.x; t[r][c + 1] = v.y; t[r][c + 2] = v.z; t[r][c + 3] = v.w;
        __syncthreads();
        ushort4 w;
        w.x = f2bf(t[c + 0][r]); w.y = f2bf(t[c + 1][r]);
        w.z = f2bf(t[c + 2][r]); w.w = f2bf(t[c + 3][r]);
        *(ushort4*)(WoT + (size_t)(n0 + r) * K + k0 + c) = w;
    }
}

// ---------------------------------------------------------------------------
// bf16 MFMA GEMM1: qkv = x @ Wqkv^T + bias -> bf16. Q cols scaled by qscale
// (0.125*log2e -> softmax via exp2). When vt_mode, V cols (>=2048) go
// transposed + Pi-permuted into vtg[b][h][d][s'] (fused transpose_v).
// ---------------------------------------------------------------------------
__global__ __launch_bounds__(256, 3)
void gemm_mfma_bf16_kernel(const ushort* __restrict__ A,
                           const ushort* __restrict__ Bt,
                           const float* __restrict__ bias,
                           ushort* __restrict__ C, int N,
                           int qscale_cols, float qscale,
                           ushort* __restrict__ vtg, int vt_mode)
{
    constexpr int K = 1024;
    __shared__ ushort As[128 * 64];
    __shared__ ushort Bs[128 * 64];

    const int tid  = threadIdx.x;
    const int wave = tid >> 6;
    const int lane = tid & 63;
    const int l16  = lane & 15;
    const int quad = lane >> 4;
    const int wm = wave & 1, wn = wave >> 1;

    const int bm = blockIdx.y * 128;
    const int bn = blockIdx.x * 128;

    const int srow = lane >> 3;
    const int lblk = (lane & 7) ^ srow;
    const ushort* Ag = A  + (size_t)(bm + wave * 32 + srow) * K + lblk * 8;
    const ushort* Bg = Bt + (size_t)(bn + wave * 32 + srow) * K + lblk * 8;
    ushort* Asl = As + wave * 32 * 64;
    ushort* Bsl = Bs + wave * 32 * 64;

    f32x4 acc[4][4];
    #pragma unroll
    for (int i = 0; i < 4; i++)
        #pragma unroll
        for (int j = 0; j < 4; j++) acc[i][j] = (f32x4){0.f, 0.f, 0.f, 0.f};

    for (int k0 = 0; k0 < K; k0 += 64) {
        __syncthreads();
        #pragma unroll
        for (int t = 0; t < 4; t++) {
            async_copy16(Ag + (size_t)t * 8 * K + k0, Asl + t * 8 * 64);
            async_copy16(Bg + (size_t)t * 8 * K + k0, Bsl + t * 8 * 64);
        }
        __syncthreads();

        #pragma unroll
        for (int s = 0; s < 2; s++) {
            bf16x8 af[4], bfr[4];
            #pragma unroll
            for (int i = 0; i < 4; i++) {
                int m = wm * 64 + i * 16 + l16;
                int n = wn * 64 + i * 16 + l16;
                af[i]  = *(const bf16x8*)&As[m * 64 + (((s * 4 + quad) ^ (m & 7)) << 3)];
                bfr[i] = *(const bf16x8*)&Bs[n * 64 + (((s * 4 + quad) ^ (n & 7)) << 3)];
            }
            #pragma unroll
            for (int i = 0; i < 4; i++)
                #pragma unroll
                for (int j = 0; j < 4; j++)
                    acc[i][j] = __builtin_amdgcn_mfma_f32_16x16x32_bf16(af[i], bfr[j], acc[i][j], 0, 0, 0);
        }
    }

    #pragma unroll
    for (int j = 0; j < 4; j++) {
        int col = bn + wn * 64 + j * 16 + l16;
        float bv = bias[col];
        if (vt_mode && col >= 2048) {
            // V -> vtg transposed + Pi: s64 = i*16+quad*4+r; Pi(s64)=(quad*4+r)*4+i
            int dfull = col - 2048;
            int hh = dfull >> 6, dd = dfull & 63;
            int bb = bm >> 11;
            int sb = ((bm & 2047) + wm * 64) >> 6;
            ushort tmp[16];
            #pragma unroll
            for (int i = 0; i < 4; i++)
                #pragma unroll
                for (int r = 0; r < 4; r++)
                    tmp[r * 4 + i] = f2bf(acc[i][j][r] + bv);
            ushort* dst = vtg + ((size_t)((bb * NH + hh) * 64 + dd)) * SEQ
                          + sb * 64 + quad * 16;
            *(uint4*)dst = *(const uint4*)tmp;
            *(uint4*)(dst + 8) = *(const uint4*)(tmp + 8);
        } else {
            float s = (col < qscale_cols) ? qscale : 1.0f;
            #pragma unroll
            for (int i = 0; i < 4; i++) {
                int row0 = bm + wm * 64 + i * 16 + quad * 4;
                #pragma unroll
                for (int r = 0; r < 4; r++)
                    C[(size_t)(row0 + r) * N + col] = f2bf((acc[i][j][r] + bv) * s);
            }
        }
    }
}

// ---------------------------------------------------------------------------
// Output projection, single-pass bf16 MFMA: C[4096][1024]f32 = attn @ WoT^T + bo.
// Tile 128(M)x64(N), BK=64, grid 512 (2+/CU), LDS 24 KB.
// ---------------------------------------------------------------------------
__global__ __launch_bounds__(256, 4)
void gemm_out_kernel(const ushort* __restrict__ A,
                     const ushort* __restrict__ Bt,
                     const float* __restrict__ bias,
                     float* __restrict__ C)
{
    constexpr int K = 1024, N = 1024;
    __shared__ ushort As[128 * 64];
    __shared__ ushort Bs[64 * 64];

    const int tid  = threadIdx.x;
    const int wave = tid >> 6;
    const int lane = tid & 63;
    const int l16  = lane & 15;
    const int quad = lane >> 4;
    const int wm = wave & 1, wn = wave >> 1;

    const int bm = blockIdx.y * 128;
    const int bn = blockIdx.x * 64;

    const int srow = lane >> 3;
    const int lblk = (lane & 7) ^ srow;
    const ushort* Ag = A  + (size_t)(bm + wave * 32 + srow) * K + lblk * 8;
    const ushort* Bg = Bt + (size_t)(bn + wave * 16 + srow) * K + lblk * 8;
    ushort* Asl = As + wave * 32 * 64;
    ushort* Bsl = Bs + wave * 16 * 64;

    f32x4 acc[4][2];
    #pragma unroll
    for (int i = 0; i < 4; i++)
        #pragma unroll
        for (int j = 0; j < 2; j++) acc[i][j] = (f32x4){0.f, 0.f, 0.f, 0.f};

    for (int k0 = 0; k0 < K; k0 += 64) {
        __syncthreads();
        #pragma unroll
        for (int t = 0; t < 4; t++)
            async_copy16(Ag + (size_t)t * 8 * K + k0, Asl + t * 8 * 64);
        #pragma unroll
        for (int t = 0; t < 2; t++)
            async_copy16(Bg + (size_t)t * 8 * K + k0, Bsl + t * 8 * 64);
        __syncthreads();

        #pragma unroll
        for (int s = 0; s < 2; s++) {
            bf16x8 af[4], bfr[2];
            #pragma unroll
            for (int i = 0; i < 4; i++) {
                int m = wm * 64 + i * 16 + l16;
                af[i] = *(const bf16x8*)&As[m * 64 + (((s * 4 + quad) ^ (m & 7)) << 3)];
            }
            #pragma unroll
            for (int j = 0; j < 2; j++) {
                int n = wn * 32 + j * 16 + l16;
                bfr[j] = *(const bf16x8*)&Bs[n * 64 + (((s * 4 + quad) ^ (n & 7)) << 3)];
            }
            #pragma unroll
            for (int i = 0; i < 4; i++)
                #pragma unroll
                for (int j = 0; j < 2; j++)
                    acc[i][j] = __builtin_amdgcn_mfma_f32_16x16x32_bf16(af[i], bfr[j], acc[i][j], 0, 0, 0);
        }
    }

    #pragma unroll
    for (int j = 0; j < 2; j++) {
        int col = bn + wn * 32 + j * 16 + l16;
        float bv = bias[col];
        #pragma unroll
        for (int i = 0; i < 4; i++) {
            int row0 = bm + wm * 64 + i * 16 + quad * 4;
            #pragma unroll
            for (int r = 0; r < 4; r++)
                C[(size_t)(row0 + r) * N + col] = acc[i][j][r] + bv;
        }
    }
}

// ---------------------------------------------------------------------------
// Flash attention v8: v6 structure (async global_load_lds staging, 2 barriers
// per iter, 112 VGPR, no reg-prefetch) + XCD-bijective block swizzle only.
// Post-mortem v7: swizzle's FETCH drop (69.7->20.5 MB) was real; reg-prefetch
// spilled to scratch (WRITE_SIZE 8->95 MB) and doubled dur. Keep the winner,
// drop the loser. Each XCD gets 4 heads x 16 qb = 64 blocks (32 CU x 2);
// K/V working set 4 x 512 KB = 2 MB resident in its 4 MB L2.
// ---------------------------------------------------------------------------
__global__ __launch_bounds__(256, 2)
void attn_mfma_v8_kernel(const ushort* __restrict__ qkvb,
                         const ushort* __restrict__ vtg,
                         ushort* __restrict__ attn)
{
    // ushort layout: Ks[2][4096] | Vs[2][4096] @8192 | Ps[4][4608] @16384
    __shared__ __align__(16) ushort smem[34816];

    const int tid  = threadIdx.x;
    const int wave = tid >> 6;
    const int qg   = wave & 1;
    const int kh   = wave >> 1;
    const int lane = tid & 63;
    const int l16  = lane & 15;
    const int quad = lane >> 4;

    // XCD swizzle: xcd = bid&7 gets heads [xcd*4, xcd*4+4), all 16 qb each.
    const int obid = blockIdx.x;
    const int qb = (obid >> 3) & 15;
    const int bh = (obid & 7) * 4 + (obid >> 7);
    const int h  = bh & (NH - 1);
    const int b  = bh >> 4;

    const int qbase = qb * 128 + qg * 64;
    const int hoff  = h * 64;

    ushort* KsH = smem + kh * 4096;
    ushort* VsH = smem + 8192 + kh * 4096;
    ushort* Psw = smem + 16384 + wave * 4608;

    bf16x8 a_q[4][2];
    #pragma unroll
    for (int mg = 0; mg < 4; mg++) {
        int qrow = b * SEQ + qbase + mg * 16 + l16;
        const ushort* qp = qkvb + (size_t)qrow * 3072 + hoff + quad * 8;
        a_q[mg][0] = *(const bf16x8*)qp;
        a_q[mg][1] = *(const bf16x8*)(qp + 32);
    }

    f32x4 o[4][4];
    f32x4 lacc[4];
    #pragma unroll
    for (int mg = 0; mg < 4; mg++) {
        lacc[mg] = (f32x4){0.f, 0.f, 0.f, 0.f};
        #pragma unroll
        for (int nt = 0; nt < 4; nt++) o[mg][nt] = (f32x4){0.f, 0.f, 0.f, 0.f};
    }

    bf16x8 b_ones;
    #pragma unroll
    for (int j = 0; j < 8; j++) b_ones[j] = (short)0x3f80;

    const ushort* kvb    = qkvb + (size_t)b * SEQ * 3072;
    const ushort* vtg_bh = vtg + (size_t)((b * NH + h) * 64) * SEQ;

    const int srow8 = lane >> 3;
    const int gblk  = ((lane & 7) ^ srow8) << 3;
    const ushort* kg = kvb + (size_t)(kh * 1024 + qg * 32 + srow8) * 3072 + 1024 + hoff + gblk;
    const ushort* vg = vtg_bh + (size_t)(qg * 32 + srow8) * SEQ + kh * 1024 + gblk;

    for (int t = 0; t < 16; t++) {
        const int k0 = t * 64;
        __syncthreads();
        #pragma unroll
        for (int c = 0; c < 4; c++) {
            async_copy16(kg + (size_t)(k0 + c * 8) * 3072, KsH + (qg * 32 + c * 8) * 64);
            async_copy16(vg + (size_t)(c * 8) * SEQ + k0,  VsH + (qg * 32 + c * 8) * 64);
        }
        __syncthreads();

        f32x4 sc[4][4];
        #pragma unroll
        for (int nt = 0; nt < 4; nt++) {
            int key = nt * 16 + l16;
            bf16x8 bk0 = *(const bf16x8*)&KsH[key * 64 + ((quad ^ (key & 7)) << 3)];
            bf16x8 bk1 = *(const bf16x8*)&KsH[key * 64 + (((4 + quad) ^ (key & 7)) << 3)];
            #pragma unroll
            for (int mg = 0; mg < 4; mg++) {
                f32x4 a = (f32x4){0.f, 0.f, 0.f, 0.f};
                a = __builtin_amdgcn_mfma_f32_16x16x32_bf16(a_q[mg][0], bk0, a, 0, 0, 0);
                a = __builtin_amdgcn_mfma_f32_16x16x32_bf16(a_q[mg][1], bk1, a, 0, 0, 0);
                sc[mg][nt] = a;
            }
        }

        #pragma unroll
        for (int mg = 0; mg < 4; mg++) {
            #pragma unroll
            for (int r = 0; r < 4; r++) {
                int q = mg * 16 + quad * 4 + r;
                uint2 pk2;
                pk2.x = pack_bf_trunc(fexp2(sc[mg][0][r]), fexp2(sc[mg][1][r]));
                pk2.y = pack_bf_trunc(fexp2(sc[mg][2][r]), fexp2(sc[mg][3][r]));
                *(uint2*)&Psw[q * 72 + l16 * 4] = pk2;
            }
        }

        asm volatile("s_waitcnt lgkmcnt(0)" ::: "memory");

        #pragma unroll
        for (int mg = 0; mg < 4; mg++) {
            bf16x8 ap0 = *(const bf16x8*)&Psw[(mg * 16 + l16) * 72 + quad * 8];
            bf16x8 ap1 = *(const bf16x8*)&Psw[(mg * 16 + l16) * 72 + 32 + quad * 8];
            #pragma unroll
            for (int nt = 0; nt < 4; nt++) {
                int d = nt * 16 + l16;
                bf16x8 bv0 = *(const bf16x8*)&VsH[d * 64 + ((quad ^ (d & 7)) << 3)];
                bf16x8 bv1 = *(const bf16x8*)&VsH[d * 64 + (((4 + quad) ^ (d & 7)) << 3)];
                o[mg][nt] = __builtin_amdgcn_mfma_f32_16x16x32_bf16(ap0, bv0, o[mg][nt], 0, 0, 0);
                o[mg][nt] = __builtin_amdgcn_mfma_f32_16x16x32_bf16(ap1, bv1, o[mg][nt], 0, 0, 0);
            }
            lacc[mg] = __builtin_amdgcn_mfma_f32_16x16x32_bf16(ap0, b_ones, lacc[mg], 0, 0, 0);
            lacc[mg] = __builtin_amdgcn_mfma_f32_16x16x32_bf16(ap1, b_ones, lacc[mg], 0, 0, 0);
        }
    }

    // combine key-halves
    __syncthreads();
    float* osc = (float*)smem;
    float* lsc = (float*)(smem + 16384);
    const int ob = qg * 4096;
    const int lb = qg * 64;
    if (kh == 1) {
        #pragma unroll
        for (int mg = 0; mg < 4; mg++) {
            #pragma unroll
            for (int nt = 0; nt < 4; nt++)
                *(f32x4*)&osc[ob + ((mg * 4 + nt) * 4 + quad) * 64 + l16 * 4] = o[mg][nt];
            if (l16 == 0) *(f32x4*)&lsc[lb + (mg * 4 + quad) * 4] = lacc[mg];
        }
    }
    __syncthreads();
    if (kh == 0) {
        #pragma unroll
        for (int mg = 0; mg < 4; mg++) {
            #pragma unroll
            for (int nt = 0; nt < 4; nt++)
                o[mg][nt] += *(const f32x4*)&osc[ob + ((mg * 4 + nt) * 4 + quad) * 64 + l16 * 4];
            lacc[mg] += *(const f32x4*)&lsc[lb + (mg * 4 + quad) * 4];
        }
        #pragma unroll
        for (int mg = 0; mg < 4; mg++) {
            #pragma unroll
            for (int r = 0; r < 4; r++) {
                float inv = 1.f / lacc[mg][r];
                int row = b * SEQ + qbase + mg * 16 + quad * 4 + r;
                size_t base = (size_t)row * HIDDEN + hoff + l16;
                #pragma unroll
                for (int nt = 0; nt < 4; nt++)
                    attn[base + nt * 16] = f2bf(o[mg][nt][r] * inv);
            }
        }
    }
}

// ---------------------------------------------------------------------------
// Fallback attention (no vtg workspace): barrier kernel staging K + Pi-V.
// ---------------------------------------------------------------------------
__global__ __launch_bounds__(512, 4)
void attn_mfma_fb_kernel(const ushort* __restrict__ qkvb,
                         ushort* __restrict__ attn)
{
    __shared__ __align__(16) ushort smem[34816];

    const int tid   = threadIdx.x;
    const int wave  = tid >> 6;
    const int wavel = wave & 3;
    const int kh    = wave >> 2;
    const int lane  = tid & 63;
    const int l16   = lane & 15;
    const int quad  = lane >> 4;

    const int qb = blockIdx.x & 15;
    const int bh = blockIdx.x >> 4;
    const int h  = bh & (NH - 1);
    const int b  = bh >> 4;

    const int qbase = qb * 128;
    const int hoff  = h * 64;

    ushort* KsH = smem + kh * 4096;
    ushort* VsH = smem + 8192 + kh * 4096;
    ushort* Psw = smem + 16384 + wave * 2304;

    bf16x8 a_q[2][2];
    #pragma unroll
    for (int mg = 0; mg < 2; mg++) {
        int qrow = b * SEQ + qbase + wavel * 32 + mg * 16 + l16;
        const ushort* qp = qkvb + (size_t)qrow * 3072 + hoff + quad * 8;
        a_q[mg][0] = *(const bf16x8*)qp;
        a_q[mg][1] = *(const bf16x8*)(qp + 32);
    }

    f32x4 o[2][4];
    f32x4 lacc[2];
    #pragma unroll
    for (int mg = 0; mg < 2; mg++) {
        lacc[mg] = (f32x4){0.f, 0.f, 0.f, 0.f};
        #pragma unroll
        for (int nt = 0; nt < 4; nt++) o[mg][nt] = (f32x4){0.f, 0.f, 0.f, 0.f};
    }

    bf16x8 b_ones;
    #pragma unroll
    for (int j = 0; j < 8; j++) b_ones[j] = (short)0x3f80;

    const ushort* kvb = qkvb + (size_t)b * SEQ * 3072;

    for (int t = 0; t < 16; t++) {
        const int k0 = t * 64;
        __syncthreads();
        {
            const int tl = tid & 255;
            #pragma unroll
            for (int i = 0; i < 2; i++) {
                int key = (tl >> 3) + 32 * i;
                int blk = tl & 7;
                const ushort* ksrc = kvb + (size_t)(kh * 1024 + k0 + key) * 3072 + 1024 + hoff + blk * 8;
                uint4 kv = *(const uint4*)ksrc;
                *(uint4*)&KsH[key * 64 + ((blk ^ (key & 7)) << 3)] = kv;
                uint4 vv = *(const uint4*)(ksrc + 1024);
                const ushort* vpp = (const ushort*)&vv;
                int pk_ = (key & 15) * 4 + (key >> 4);
                #pragma unroll
                for (int j = 0; j < 8; j++) {
                    int d = blk * 8 + j;
                    VsH[d * 64 + (((pk_ >> 3) ^ (d & 7)) << 3) + (pk_ & 7)] = vpp[j];
                }
            }
        }
        __syncthreads();

        f32x4 sc[2][4];
        #pragma unroll
        for (int nt = 0; nt < 4; nt++) {
            int key = nt * 16 + l16;
            bf16x8 bk0 = *(const bf16x8*)&KsH[key * 64 + ((quad ^ (key & 7)) << 3)];
            bf16x8 bk1 = *(const bf16x8*)&KsH[key * 64 + (((4 + quad) ^ (key & 7)) << 3)];
            #pragma unroll
            for (int mg = 0; mg < 2; mg++) {
                f32x4 a = (f32x4){0.f, 0.f, 0.f, 0.f};
                a = __builtin_amdgcn_mfma_f32_16x16x32_bf16(a_q[mg][0], bk0, a, 0, 0, 0);
                a = __builtin_amdgcn_mfma_f32_16x16x32_bf16(a_q[mg][1], bk1, a, 0, 0, 0);
                sc[mg][nt] = a;
            }
        }

        #pragma unroll
        for (int mg = 0; mg < 2; mg++) {
            #pragma unroll
            for (int r = 0; r < 4; r++) {
                int q = mg * 16 + quad * 4 + r;
                uint2 pk2;
                pk2.x = pack_bf_trunc(fexp2(sc[mg][0][r]), fexp2(sc[mg][1][r]));
                pk2.y = pack_bf_trunc(fexp2(sc[mg][2][r]), fexp2(sc[mg][3][r]));
                *(uint2*)&Psw[q * 72 + l16 * 4] = pk2;
            }
        }

        asm volatile("s_waitcnt lgkmcnt(0)" ::: "memory");
        bf16x8 a_p[2][2];
        #pragma unroll
        for (int mg = 0; mg < 2; mg++) {
            a_p[mg][0] = *(const bf16x8*)&Psw[(mg * 16 + l16) * 72 + quad * 8];
            a_p[mg][1] = *(const bf16x8*)&Psw[(mg * 16 + l16) * 72 + 32 + quad * 8];
        }

        #pragma unroll
        for (int nt = 0; nt < 4; nt++) {
            int d = nt * 16 + l16;
            bf16x8 bv0 = *(const bf16x8*)&VsH[d * 64 + ((quad ^ (d & 7)) << 3)];
            bf16x8 bv1 = *(const bf16x8*)&VsH[d * 64 + (((4 + quad) ^ (d & 7)) << 3)];
            #pragma unroll
            for (int mg = 0; mg < 2; mg++) {
                o[mg][nt] = __builtin_amdgcn_mfma_f32_16x16x32_bf16(a_p[mg][0], bv0, o[mg][nt], 0, 0, 0);
                o[mg][nt] = __builtin_amdgcn_mfma_f32_16x16x32_bf16(a_p[mg][1], bv1, o[mg][nt], 0, 0, 0);
            }
        }
        #pragma unroll
        for (int mg = 0; mg < 2; mg++) {
            lacc[mg] = __builtin_amdgcn_mfma_f32_16x16x32_bf16(a_p[mg][0], b_ones, lacc[mg], 0, 0, 0);
            lacc[mg] = __builtin_amdgcn_mfma_f32_16x16x32_bf16(a_p[mg][1], b_ones, lacc[mg], 0, 0, 0);
        }
    }

    __syncthreads();
    float* osc = (float*)smem;
    float* lsc = (float*)(smem + 16384);
    const int fo = wavel * 2048 + quad * 64 + l16 * 4;
    const int fl = wavel * 512 + quad * 64 + l16 * 4;
    if (kh == 1) {
        #pragma unroll
        for (int mg = 0; mg < 2; mg++) {
            #pragma unroll
            for (int nt = 0; nt < 4; nt++)
                *(f32x4*)&osc[fo + (mg * 4 + nt) * 256] = o[mg][nt];
            *(f32x4*)&lsc[fl + mg * 256] = lacc[mg];
        }
    }
    __syncthreads();
    if (kh == 0) {
        #pragma unroll
        for (int mg = 0; mg < 2; mg++) {
            #pragma unroll
            for (int nt = 0; nt < 4; nt++)
                o[mg][nt] += *(const f32x4*)&osc[fo + (mg * 4 + nt) * 256];
            lacc[mg] += *(const f32x4*)&lsc[fl + mg * 256];
        }
        #pragma unroll
        for (int mg = 0; mg < 2; mg++) {
            #pragma unroll
            for (int r = 0; r < 4; r++) {
                float inv = 1.f / lacc[mg][r];
                int row = b * SEQ + qbase + wavel * 32 + mg * 16 + quad * 4 + r;
                size_t base = (size_t)row * HIDDEN + hoff + l16;
                #pragma unroll
                for (int nt = 0; nt < 4; nt++)
                    attn[base + nt * 16] = f2bf(o[mg][nt][r] * inv);
            }
        }
    }
}

extern "C" void kernel_launch(void* const* d_in, const int* in_sizes, int n_in,
                              void* d_out, int out_size, void* d_ws, size_t ws_size,
                              hipStream_t stream) {
    const float* x    = (const float*)d_in[0];
    const float* Wqkv = (const float*)d_in[1];
    const float* bqkv = (const float*)d_in[2];
    const float* Wo   = (const float*)d_in[3];
    const float* bo   = (const float*)d_in[4];
    float* out = (float*)d_out;

    const int M = BATCH * SEQ;                   // 4096
    const size_t MB = 1024 * 1024;

    // workspace (48 MB):
    //   [0,24) qkvb | [24,32) attn (xb overlaps: prep/GEMM1 only)
    //   [32,38) Wt (prep/GEMM1) | [38,40) WoT (prep->GEMM3) | [40,48) vtg
    char* ws = (char*)d_ws;
    ushort* qkvb = (ushort*)ws;
    ushort* attn = (ushort*)(ws + 24 * MB);
    ushort* xb   = (ushort*)(ws + 24 * MB);
    ushort* Wt   = (ushort*)(ws + 32 * MB);
    ushort* WoT  = (ushort*)(ws + 38 * MB);
    ushort* vtg  = (ushort*)(ws + 40 * MB);
    const int use_vtg = (ws_size >= 48 * MB) ? 1 : 0;

    const float qscale = 0.125f * 1.44269504088896f;   // fold log2e -> exp2 softmax

    // 0) fused preps (x->bf16, Wqkv transpose, Wo transpose)
    prep_kernel<<<8192, 256, 0, stream>>>(x, Wqkv, Wo, xb, Wt, WoT);

    // 1) qkv = (x @ Wqkv + bqkv) -> bf16; V written transposed to vtg when able
    {
        dim3 grid((3 * HIDDEN) / 128, M / 128);
        gemm_mfma_bf16_kernel<<<grid, 256, 0, stream>>>(xb, Wt, bqkv, qkvb,
                                                        3 * HIDDEN, HIDDEN, qscale,
                                                        vtg, use_vtg);
    }

    // 2) flash attention -> attn bf16
    if (use_vtg) {
        attn_mfma_v8_kernel<<<BATCH * NH * (SEQ / 128), 256, 0, stream>>>(
            qkvb, vtg, attn);
    } else {
        attn_mfma_fb_kernel<<<BATCH * NH * (SEQ / 128), 512, 0, stream>>>(
            qkvb, attn);
    }

    // 3) out = attn @ Wo + bo (single-pass bf16 MFMA)
    {
        dim3 grid(HIDDEN / 64, M / 128);
        gemm_out_kernel<<<grid, 256, 0, stream>>>(attn, WoT, bo, out);
    }
}

// Round 3
// 178.260 us; speedup vs baseline: 1.1958x; 1.0154x over previous
//
#include <hip/hip_runtime.h>
#include <hip/hip_bf16.h>

#define HIDDEN 1024
#define NH 16
#define BATCH 2
#define SEQ 2048

typedef __attribute__((ext_vector_type(8))) short bf16x8;
typedef __attribute__((ext_vector_type(4))) float f32x4;

__device__ __forceinline__ ushort f2bf(float f) {
    __hip_bfloat16 h = __float2bfloat16(f);
    return *reinterpret_cast<ushort*>(&h);
}
__device__ __forceinline__ float fexp2(float x) {
#if __has_builtin(__builtin_amdgcn_exp2f)
    return __builtin_amdgcn_exp2f(x);
#else
    return exp2f(x);
#endif
}
// pack trunc-bf16(a) low, trunc-bf16(b) high (1 v_perm)
__device__ __forceinline__ uint pack_bf_trunc(float a, float b) {
    return __builtin_amdgcn_perm(__float_as_uint(b), __float_as_uint(a), 0x07060302u);
}

// async global->LDS, 16B per lane
__device__ __forceinline__ void async_copy16(const ushort* g, ushort* l) {
    __builtin_amdgcn_global_load_lds((const __attribute__((address_space(1))) void*)g,
                                     (__attribute__((address_space(3))) void*)l,
                                     16, 0, 0);
}

// ---------------------------------------------------------------------------
// Fused prep: [0,4096) x->bf16 | [4096,7168) Wqkv transpose | [7168,8192) Wo transpose
// ---------------------------------------------------------------------------
__global__ void prep_kernel(const float* __restrict__ x,
                            const float* __restrict__ Wqkv,
                            const float* __restrict__ Wo,
                            ushort* __restrict__ xb,
                            ushort* __restrict__ Wt,
                            ushort* __restrict__ WoT)
{
    __shared__ float t[32][33];
    const int bid = blockIdx.x;
    const int tid = threadIdx.x;

    if (bid < 4096) {
        int i = (bid * 256 + tid) * 4;
        float4 v = *(const float4*)(x + i);
        ushort4 w;
        w.x = f2bf(v.x); w.y = f2bf(v.y); w.z = f2bf(v.z); w.w = f2bf(v.w);
        *(ushort4*)(xb + i) = w;
        return;
    }
    const int r = tid >> 3;
    const int c = (tid & 7) * 4;
    if (bid < 7168) {
        int tt = bid - 4096;
        int k0 = (tt & 31) * 32;
        int n0 = (tt >> 5) * 32;
        const int N = 3 * HIDDEN, K = HIDDEN;
        float4 v = *(const float4*)(Wqkv + (size_t)(k0 + r) * N + n0 + c);
        t[r][c] = v.x; t[r][c + 1] = v.y; t[r][c + 2] = v.z; t[r][c + 3] = v.w;
        __syncthreads();
        ushort4 w;
        w.x = f2bf(t[c + 0][r]); w.y = f2bf(t[c + 1][r]);
        w.z = f2bf(t[c + 2][r]); w.w = f2bf(t[c + 3][r]);
        *(ushort4*)(Wt + (size_t)(n0 + r) * K + k0 + c) = w;
    } else {
        int tt = bid - 7168;
        int k0 = (tt & 31) * 32;
        int n0 = (tt >> 5) * 32;
        const int N = HIDDEN, K = HIDDEN;
        float4 v = *(const float4*)(Wo + (size_t)(k0 + r) * N + n0 + c);
        t[r][c] = v.x; t[r][c + 1] = v.y; t[r][c + 2] = v.z; t[r][c + 3] = v.w;
        __syncthreads();
        ushort4 w;
        w.x = f2bf(t[c + 0][r]); w.y = f2bf(t[c + 1][r]);
        w.z = f2bf(t[c + 2][r]); w.w = f2bf(t[c + 3][r]);
        *(ushort4*)(WoT + (size_t)(n0 + r) * K + k0 + c) = w;
    }
}

// ---------------------------------------------------------------------------
// bf16 MFMA GEMM1: qkv = x @ Wqkv^T + bias -> bf16. Q cols scaled by qscale
// (0.125*log2e -> softmax via exp2). When vt_mode, V cols (>=2048) go
// transposed + Pi-permuted into vtg[b][h][d][s'] (fused transpose_v).
// ---------------------------------------------------------------------------
__global__ __launch_bounds__(256, 3)
void gemm_mfma_bf16_kernel(const ushort* __restrict__ A,
                           const ushort* __restrict__ Bt,
                           const float* __restrict__ bias,
                           ushort* __restrict__ C, int N,
                           int qscale_cols, float qscale,
                           ushort* __restrict__ vtg, int vt_mode)
{
    constexpr int K = 1024;
    __shared__ ushort As[128 * 64];
    __shared__ ushort Bs[128 * 64];

    const int tid  = threadIdx.x;
    const int wave = tid >> 6;
    const int lane = tid & 63;
    const int l16  = lane & 15;
    const int quad = lane >> 4;
    const int wm = wave & 1, wn = wave >> 1;

    const int bm = blockIdx.y * 128;
    const int bn = blockIdx.x * 128;

    const int srow = lane >> 3;
    const int lblk = (lane & 7) ^ srow;
    const ushort* Ag = A  + (size_t)(bm + wave * 32 + srow) * K + lblk * 8;
    const ushort* Bg = Bt + (size_t)(bn + wave * 32 + srow) * K + lblk * 8;
    ushort* Asl = As + wave * 32 * 64;
    ushort* Bsl = Bs + wave * 32 * 64;

    f32x4 acc[4][4];
    #pragma unroll
    for (int i = 0; i < 4; i++)
        #pragma unroll
        for (int j = 0; j < 4; j++) acc[i][j] = (f32x4){0.f, 0.f, 0.f, 0.f};

    for (int k0 = 0; k0 < K; k0 += 64) {
        __syncthreads();
        #pragma unroll
        for (int t = 0; t < 4; t++) {
            async_copy16(Ag + (size_t)t * 8 * K + k0, Asl + t * 8 * 64);
            async_copy16(Bg + (size_t)t * 8 * K + k0, Bsl + t * 8 * 64);
        }
        __syncthreads();

        #pragma unroll
        for (int s = 0; s < 2; s++) {
            bf16x8 af[4], bfr[4];
            #pragma unroll
            for (int i = 0; i < 4; i++) {
                int m = wm * 64 + i * 16 + l16;
                int n = wn * 64 + i * 16 + l16;
                af[i]  = *(const bf16x8*)&As[m * 64 + (((s * 4 + quad) ^ (m & 7)) << 3)];
                bfr[i] = *(const bf16x8*)&Bs[n * 64 + (((s * 4 + quad) ^ (n & 7)) << 3)];
            }
            #pragma unroll
            for (int i = 0; i < 4; i++)
                #pragma unroll
                for (int j = 0; j < 4; j++)
                    acc[i][j] = __builtin_amdgcn_mfma_f32_16x16x32_bf16(af[i], bfr[j], acc[i][j], 0, 0, 0);
        }
    }

    #pragma unroll
    for (int j = 0; j < 4; j++) {
        int col = bn + wn * 64 + j * 16 + l16;
        float bv = bias[col];
        if (vt_mode && col >= 2048) {
            // V -> vtg transposed + Pi: s64 = i*16+quad*4+r; Pi(s64)=(quad*4+r)*4+i
            int dfull = col - 2048;
            int hh = dfull >> 6, dd = dfull & 63;
            int bb = bm >> 11;
            int sb = ((bm & 2047) + wm * 64) >> 6;
            ushort tmp[16];
            #pragma unroll
            for (int i = 0; i < 4; i++)
                #pragma unroll
                for (int r = 0; r < 4; r++)
                    tmp[r * 4 + i] = f2bf(acc[i][j][r] + bv);
            ushort* dst = vtg + ((size_t)((bb * NH + hh) * 64 + dd)) * SEQ
                          + sb * 64 + quad * 16;
            *(uint4*)dst = *(const uint4*)tmp;
            *(uint4*)(dst + 8) = *(const uint4*)(tmp + 8);
        } else {
            float s = (col < qscale_cols) ? qscale : 1.0f;
            #pragma unroll
            for (int i = 0; i < 4; i++) {
                int row0 = bm + wm * 64 + i * 16 + quad * 4;
                #pragma unroll
                for (int r = 0; r < 4; r++)
                    C[(size_t)(row0 + r) * N + col] = f2bf((acc[i][j][r] + bv) * s);
            }
        }
    }
}

// ---------------------------------------------------------------------------
// Output projection, single-pass bf16 MFMA: C[4096][1024]f32 = attn @ WoT^T + bo.
// Tile 128(M)x64(N), BK=64, grid 512 (2+/CU), LDS 24 KB.
// ---------------------------------------------------------------------------
__global__ __launch_bounds__(256, 4)
void gemm_out_kernel(const ushort* __restrict__ A,
                     const ushort* __restrict__ Bt,
                     const float* __restrict__ bias,
                     float* __restrict__ C)
{
    constexpr int K = 1024, N = 1024;
    __shared__ ushort As[128 * 64];
    __shared__ ushort Bs[64 * 64];

    const int tid  = threadIdx.x;
    const int wave = tid >> 6;
    const int lane = tid & 63;
    const int l16  = lane & 15;
    const int quad = lane >> 4;
    const int wm = wave & 1, wn = wave >> 1;

    const int bm = blockIdx.y * 128;
    const int bn = blockIdx.x * 64;

    const int srow = lane >> 3;
    const int lblk = (lane & 7) ^ srow;
    const ushort* Ag = A  + (size_t)(bm + wave * 32 + srow) * K + lblk * 8;
    const ushort* Bg = Bt + (size_t)(bn + wave * 16 + srow) * K + lblk * 8;
    ushort* Asl = As + wave * 32 * 64;
    ushort* Bsl = Bs + wave * 16 * 64;

    f32x4 acc[4][2];
    #pragma unroll
    for (int i = 0; i < 4; i++)
        #pragma unroll
        for (int j = 0; j < 2; j++) acc[i][j] = (f32x4){0.f, 0.f, 0.f, 0.f};

    for (int k0 = 0; k0 < K; k0 += 64) {
        __syncthreads();
        #pragma unroll
        for (int t = 0; t < 4; t++)
            async_copy16(Ag + (size_t)t * 8 * K + k0, Asl + t * 8 * 64);
        #pragma unroll
        for (int t = 0; t < 2; t++)
            async_copy16(Bg + (size_t)t * 8 * K + k0, Bsl + t * 8 * 64);
        __syncthreads();

        #pragma unroll
        for (int s = 0; s < 2; s++) {
            bf16x8 af[4], bfr[2];
            #pragma unroll
            for (int i = 0; i < 4; i++) {
                int m = wm * 64 + i * 16 + l16;
                af[i] = *(const bf16x8*)&As[m * 64 + (((s * 4 + quad) ^ (m & 7)) << 3)];
            }
            #pragma unroll
            for (int j = 0; j < 2; j++) {
                int n = wn * 32 + j * 16 + l16;
                bfr[j] = *(const bf16x8*)&Bs[n * 64 + (((s * 4 + quad) ^ (n & 7)) << 3)];
            }
            #pragma unroll
            for (int i = 0; i < 4; i++)
                #pragma unroll
                for (int j = 0; j < 2; j++)
                    acc[i][j] = __builtin_amdgcn_mfma_f32_16x16x32_bf16(af[i], bfr[j], acc[i][j], 0, 0, 0);
        }
    }

    #pragma unroll
    for (int j = 0; j < 2; j++) {
        int col = bn + wn * 32 + j * 16 + l16;
        float bv = bias[col];
        #pragma unroll
        for (int i = 0; i < 4; i++) {
            int row0 = bm + wm * 64 + i * 16 + quad * 4;
            #pragma unroll
            for (int r = 0; r < 4; r++)
                C[(size_t)(row0 + r) * N + col] = acc[i][j][r] + bv;
        }
    }
}

// ---------------------------------------------------------------------------
// Flash attention v9: occupancy + pipeline restructure.
// Post-mortem v8: XCD swizzle fixed locality (FETCH 69.7->12.3 MB) but dur
// barely moved -> structure-bound, not memory-bound. v8 had 8 waves/CU with
// MFMA/VALU phases in near-lockstep (MfmaUtil 30 + VALUBusy 29, ~40% idle).
// v9: 512 thr = 8 waves, each owning 16 q-rows, all 2048 keys in 32 tiles.
//  - no key-half split -> no combine epilogue, Ps shrinks to 18 KB
//  - K/V double-buffered (LDS 50 KB, still 2 blocks/CU) -> 16 waves/CU
//  - stage tile t+1 at iter top, ONE barrier per iter; the barrier's vmcnt
//    drain lands after ~1000cy compute -> staging latency fully hidden.
// Same K XOR-swizzle / Pi-ordered V / stride-72 Ps layouts as v8.
// ---------------------------------------------------------------------------
__global__ __launch_bounds__(512, 4)
void attn_mfma_v9_kernel(const ushort* __restrict__ qkvb,
                         const ushort* __restrict__ vtg,
                         ushort* __restrict__ attn)
{
    // ushort layout: K[2][4096] | V[2][4096] @8192 | Ps[8][1152] @16384
    // total 25600 ush = 50 KB
    __shared__ __align__(16) ushort smem[25600];

    const int tid  = threadIdx.x;
    const int wave = tid >> 6;
    const int lane = tid & 63;
    const int l16  = lane & 15;
    const int quad = lane >> 4;

    // XCD swizzle: xcd = bid&7 gets heads [xcd*4, xcd*4+4), all 16 qb each.
    const int obid = blockIdx.x;
    const int qb = (obid >> 3) & 15;
    const int bh = (obid & 7) * 4 + (obid >> 7);
    const int h  = bh & (NH - 1);
    const int b  = bh >> 4;

    const int qbase = qb * 128 + wave * 16;   // 16 q-rows per wave
    const int hoff  = h * 64;

    ushort* Psw = smem + 16384 + wave * 1152;

    // Q fragment: 16 rows, d = quad*8 (+32 for second k-slice)
    bf16x8 a_q0, a_q1;
    {
        int qrow = b * SEQ + qbase + l16;
        const ushort* qp = qkvb + (size_t)qrow * 3072 + hoff + quad * 8;
        a_q0 = *(const bf16x8*)qp;
        a_q1 = *(const bf16x8*)(qp + 32);
    }

    f32x4 o[4];
    f32x4 lacc = (f32x4){0.f, 0.f, 0.f, 0.f};
    #pragma unroll
    for (int nt = 0; nt < 4; nt++) o[nt] = (f32x4){0.f, 0.f, 0.f, 0.f};

    bf16x8 b_ones;
    #pragma unroll
    for (int j = 0; j < 8; j++) b_ones[j] = (short)0x3f80;

    const ushort* kvb    = qkvb + (size_t)b * SEQ * 3072;
    const ushort* vtg_bh = vtg + (size_t)((b * NH + h) * 64) * SEQ;

    // staging: 512 threads x 16B = 8 KB = one 64x64 bf16 tile per array.
    // thread t covers K row (wave*8 + srow8); global col pre-swizzled so the
    // linear LDS dest (base + lane*16B) yields the XOR-swizzled layout.
    const int srow8 = lane >> 3;
    const int gblk  = ((lane & 7) ^ srow8) << 3;
    const ushort* kg = kvb + (size_t)(wave * 8 + srow8) * 3072 + 1024 + hoff + gblk;
    const ushort* vg = vtg_bh + (size_t)(wave * 8 + srow8) * SEQ + gblk;

    ushort* k_dst = smem + wave * 512;          // + cur*4096
    ushort* v_dst = smem + 8192 + wave * 512;   // + cur*4096

    // prologue: stage tile 0 into buf 0; barrier drains vmcnt
    async_copy16(kg, k_dst);
    async_copy16(vg, v_dst);
    __syncthreads();

    int cur = 0;
    for (int t = 0; t < 32; t++) {
        // stage tile t+1 into the other buffer (no drain here)
        if (t < 31) {
            const int k0n = (t + 1) * 64;
            async_copy16(kg + (size_t)k0n * 3072, k_dst + ((cur ^ 1) << 12));
            async_copy16(vg + k0n,                v_dst + ((cur ^ 1) << 12));
        }
        const ushort* Ks = smem + (cur << 12);
        const ushort* Vs = smem + 8192 + (cur << 12);

        // QK^T: sc[nt] covers keys nt*16..nt*16+15 for this wave's 16 q-rows
        f32x4 sc[4];
        #pragma unroll
        for (int nt = 0; nt < 4; nt++) {
            int key = nt * 16 + l16;
            bf16x8 bk0 = *(const bf16x8*)&Ks[key * 64 + ((quad ^ (key & 7)) << 3)];
            bf16x8 bk1 = *(const bf16x8*)&Ks[key * 64 + (((4 + quad) ^ (key & 7)) << 3)];
            f32x4 a = (f32x4){0.f, 0.f, 0.f, 0.f};
            a = __builtin_amdgcn_mfma_f32_16x16x32_bf16(a_q0, bk0, a, 0, 0, 0);
            a = __builtin_amdgcn_mfma_f32_16x16x32_bf16(a_q1, bk1, a, 0, 0, 0);
            sc[nt] = a;
        }

        // softmax (exp2, Q pre-scaled) -> Pi-packed trunc-bf16 P rows in LDS
        #pragma unroll
        for (int r = 0; r < 4; r++) {
            int q = quad * 4 + r;
            uint2 pk2;
            pk2.x = pack_bf_trunc(fexp2(sc[0][r]), fexp2(sc[1][r]));
            pk2.y = pack_bf_trunc(fexp2(sc[2][r]), fexp2(sc[3][r]));
            *(uint2*)&Psw[q * 72 + l16 * 4] = pk2;
        }

        asm volatile("s_waitcnt lgkmcnt(0)" ::: "memory");

        // PV + l via ones-MFMA
        bf16x8 ap0 = *(const bf16x8*)&Psw[l16 * 72 + quad * 8];
        bf16x8 ap1 = *(const bf16x8*)&Psw[l16 * 72 + 32 + quad * 8];
        #pragma unroll
        for (int nt = 0; nt < 4; nt++) {
            int d = nt * 16 + l16;
            bf16x8 bv0 = *(const bf16x8*)&Vs[d * 64 + ((quad ^ (d & 7)) << 3)];
            bf16x8 bv1 = *(const bf16x8*)&Vs[d * 64 + (((4 + quad) ^ (d & 7)) << 3)];
            o[nt] = __builtin_amdgcn_mfma_f32_16x16x32_bf16(ap0, bv0, o[nt], 0, 0, 0);
            o[nt] = __builtin_amdgcn_mfma_f32_16x16x32_bf16(ap1, bv1, o[nt], 0, 0, 0);
        }
        lacc = __builtin_amdgcn_mfma_f32_16x16x32_bf16(ap0, b_ones, lacc, 0, 0, 0);
        lacc = __builtin_amdgcn_mfma_f32_16x16x32_bf16(ap1, b_ones, lacc, 0, 0, 0);

        // everyone done reading buf[cur]; tile t+1 loads drained by barrier
        __syncthreads();
        cur ^= 1;
    }

    // epilogue: per-wave, no cross-wave combine
    #pragma unroll
    for (int r = 0; r < 4; r++) {
        float inv = 1.f / lacc[r];
        int row = b * SEQ + qbase + quad * 4 + r;
        size_t base = (size_t)row * HIDDEN + hoff + l16;
        #pragma unroll
        for (int nt = 0; nt < 4; nt++)
            attn[base + nt * 16] = f2bf(o[nt][r] * inv);
    }
}

// ---------------------------------------------------------------------------
// Fallback attention (no vtg workspace): barrier kernel staging K + Pi-V.
// ---------------------------------------------------------------------------
__global__ __launch_bounds__(512, 4)
void attn_mfma_fb_kernel(const ushort* __restrict__ qkvb,
                         ushort* __restrict__ attn)
{
    __shared__ __align__(16) ushort smem[34816];

    const int tid   = threadIdx.x;
    const int wave  = tid >> 6;
    const int wavel = wave & 3;
    const int kh    = wave >> 2;
    const int lane  = tid & 63;
    const int l16   = lane & 15;
    const int quad  = lane >> 4;

    const int qb = blockIdx.x & 15;
    const int bh = blockIdx.x >> 4;
    const int h  = bh & (NH - 1);
    const int b  = bh >> 4;

    const int qbase = qb * 128;
    const int hoff  = h * 64;

    ushort* KsH = smem + kh * 4096;
    ushort* VsH = smem + 8192 + kh * 4096;
    ushort* Psw = smem + 16384 + wave * 2304;

    bf16x8 a_q[2][2];
    #pragma unroll
    for (int mg = 0; mg < 2; mg++) {
        int qrow = b * SEQ + qbase + wavel * 32 + mg * 16 + l16;
        const ushort* qp = qkvb + (size_t)qrow * 3072 + hoff + quad * 8;
        a_q[mg][0] = *(const bf16x8*)qp;
        a_q[mg][1] = *(const bf16x8*)(qp + 32);
    }

    f32x4 o[2][4];
    f32x4 lacc[2];
    #pragma unroll
    for (int mg = 0; mg < 2; mg++) {
        lacc[mg] = (f32x4){0.f, 0.f, 0.f, 0.f};
        #pragma unroll
        for (int nt = 0; nt < 4; nt++) o[mg][nt] = (f32x4){0.f, 0.f, 0.f, 0.f};
    }

    bf16x8 b_ones;
    #pragma unroll
    for (int j = 0; j < 8; j++) b_ones[j] = (short)0x3f80;

    const ushort* kvb = qkvb + (size_t)b * SEQ * 3072;

    for (int t = 0; t < 16; t++) {
        const int k0 = t * 64;
        __syncthreads();
        {
            const int tl = tid & 255;
            #pragma unroll
            for (int i = 0; i < 2; i++) {
                int key = (tl >> 3) + 32 * i;
                int blk = tl & 7;
                const ushort* ksrc = kvb + (size_t)(kh * 1024 + k0 + key) * 3072 + 1024 + hoff + blk * 8;
                uint4 kv = *(const uint4*)ksrc;
                *(uint4*)&KsH[key * 64 + ((blk ^ (key & 7)) << 3)] = kv;
                uint4 vv = *(const uint4*)(ksrc + 1024);
                const ushort* vpp = (const ushort*)&vv;
                int pk_ = (key & 15) * 4 + (key >> 4);
                #pragma unroll
                for (int j = 0; j < 8; j++) {
                    int d = blk * 8 + j;
                    VsH[d * 64 + (((pk_ >> 3) ^ (d & 7)) << 3) + (pk_ & 7)] = vpp[j];
                }
            }
        }
        __syncthreads();

        f32x4 sc[2][4];
        #pragma unroll
        for (int nt = 0; nt < 4; nt++) {
            int key = nt * 16 + l16;
            bf16x8 bk0 = *(const bf16x8*)&KsH[key * 64 + ((quad ^ (key & 7)) << 3)];
            bf16x8 bk1 = *(const bf16x8*)&KsH[key * 64 + (((4 + quad) ^ (key & 7)) << 3)];
            #pragma unroll
            for (int mg = 0; mg < 2; mg++) {
                f32x4 a = (f32x4){0.f, 0.f, 0.f, 0.f};
                a = __builtin_amdgcn_mfma_f32_16x16x32_bf16(a_q[mg][0], bk0, a, 0, 0, 0);
                a = __builtin_amdgcn_mfma_f32_16x16x32_bf16(a_q[mg][1], bk1, a, 0, 0, 0);
                sc[mg][nt] = a;
            }
        }

        #pragma unroll
        for (int mg = 0; mg < 2; mg++) {
            #pragma unroll
            for (int r = 0; r < 4; r++) {
                int q = mg * 16 + quad * 4 + r;
                uint2 pk2;
                pk2.x = pack_bf_trunc(fexp2(sc[mg][0][r]), fexp2(sc[mg][1][r]));
                pk2.y = pack_bf_trunc(fexp2(sc[mg][2][r]), fexp2(sc[mg][3][r]));
                *(uint2*)&Psw[q * 72 + l16 * 4] = pk2;
            }
        }

        asm volatile("s_waitcnt lgkmcnt(0)" ::: "memory");
        bf16x8 a_p[2][2];
        #pragma unroll
        for (int mg = 0; mg < 2; mg++) {
            a_p[mg][0] = *(const bf16x8*)&Psw[(mg * 16 + l16) * 72 + quad * 8];
            a_p[mg][1] = *(const bf16x8*)&Psw[(mg * 16 + l16) * 72 + 32 + quad * 8];
        }

        #pragma unroll
        for (int nt = 0; nt < 4; nt++) {
            int d = nt * 16 + l16;
            bf16x8 bv0 = *(const bf16x8*)&VsH[d * 64 + ((quad ^ (d & 7)) << 3)];
            bf16x8 bv1 = *(const bf16x8*)&VsH[d * 64 + (((4 + quad) ^ (d & 7)) << 3)];
            #pragma unroll
            for (int mg = 0; mg < 2; mg++) {
                o[mg][nt] = __builtin_amdgcn_mfma_f32_16x16x32_bf16(a_p[mg][0], bv0, o[mg][nt], 0, 0, 0);
                o[mg][nt] = __builtin_amdgcn_mfma_f32_16x16x32_bf16(a_p[mg][1], bv1, o[mg][nt], 0, 0, 0);
            }
        }
        #pragma unroll
        for (int mg = 0; mg < 2; mg++) {
            lacc[mg] = __builtin_amdgcn_mfma_f32_16x16x32_bf16(a_p[mg][0], b_ones, lacc[mg], 0, 0, 0);
            lacc[mg] = __builtin_amdgcn_mfma_f32_16x16x32_bf16(a_p[mg][1], b_ones, lacc[mg], 0, 0, 0);
        }
    }

    __syncthreads();
    float* osc = (float*)smem;
    float* lsc = (float*)(smem + 16384);
    const int fo = wavel * 2048 + quad * 64 + l16 * 4;
    const int fl = wavel * 512 + quad * 64 + l16 * 4;
    if (kh == 1) {
        #pragma unroll
        for (int mg = 0; mg < 2; mg++) {
            #pragma unroll
            for (int nt = 0; nt < 4; nt++)
                *(f32x4*)&osc[fo + (mg * 4 + nt) * 256] = o[mg][nt];
            *(f32x4*)&lsc[fl + mg * 256] = lacc[mg];
        }
    }
    __syncthreads();
    if (kh == 0) {
        #pragma unroll
        for (int mg = 0; mg < 2; mg++) {
            #pragma unroll
            for (int nt = 0; nt < 4; nt++)
                o[mg][nt] += *(const f32x4*)&osc[fo + (mg * 4 + nt) * 256];
            lacc[mg] += *(const f32x4*)&lsc[fl + mg * 256];
        }
        #pragma unroll
        for (int mg = 0; mg < 2; mg++) {
            #pragma unroll
            for (int r = 0; r < 4; r++) {
                float inv = 1.f / lacc[mg][r];
                int row = b * SEQ + qbase + wavel * 32 + mg * 16 + quad * 4 + r;
                size_t base = (size_t)row * HIDDEN + hoff + l16;
                #pragma unroll
                for (int nt = 0; nt < 4; nt++)
                    attn[base + nt * 16] = f2bf(o[mg][nt][r] * inv);
            }
        }
    }
}

extern "C" void kernel_launch(void* const* d_in, const int* in_sizes, int n_in,
                              void* d_out, int out_size, void* d_ws, size_t ws_size,
                              hipStream_t stream) {
    const float* x    = (const float*)d_in[0];
    const float* Wqkv = (const float*)d_in[1];
    const float* bqkv = (const float*)d_in[2];
    const float* Wo   = (const float*)d_in[3];
    const float* bo   = (const float*)d_in[4];
    float* out = (float*)d_out;

    const int M = BATCH * SEQ;                   // 4096
    const size_t MB = 1024 * 1024;

    // workspace (48 MB):
    //   [0,24) qkvb | [24,32) attn (xb overlaps: prep/GEMM1 only)
    //   [32,38) Wt (prep/GEMM1) | [38,40) WoT (prep->GEMM3) | [40,48) vtg
    char* ws = (char*)d_ws;
    ushort* qkvb = (ushort*)ws;
    ushort* attn = (ushort*)(ws + 24 * MB);
    ushort* xb   = (ushort*)(ws + 24 * MB);
    ushort* Wt   = (ushort*)(ws + 32 * MB);
    ushort* WoT  = (ushort*)(ws + 38 * MB);
    ushort* vtg  = (ushort*)(ws + 40 * MB);
    const int use_vtg = (ws_size >= 48 * MB) ? 1 : 0;

    const float qscale = 0.125f * 1.44269504088896f;   // fold log2e -> exp2 softmax

    // 0) fused preps (x->bf16, Wqkv transpose, Wo transpose)
    prep_kernel<<<8192, 256, 0, stream>>>(x, Wqkv, Wo, xb, Wt, WoT);

    // 1) qkv = (x @ Wqkv + bqkv) -> bf16; V written transposed to vtg when able
    {
        dim3 grid((3 * HIDDEN) / 128, M / 128);
        gemm_mfma_bf16_kernel<<<grid, 256, 0, stream>>>(xb, Wt, bqkv, qkvb,
                                                        3 * HIDDEN, HIDDEN, qscale,
                                                        vtg, use_vtg);
    }

    // 2) flash attention -> attn bf16
    if (use_vtg) {
        attn_mfma_v9_kernel<<<BATCH * NH * (SEQ / 128), 512, 0, stream>>>(
            qkvb, vtg, attn);
    } else {
        attn_mfma_fb_kernel<<<BATCH * NH * (SEQ / 128), 512, 0, stream>>>(
            qkvb, attn);
    }

    // 3) out = attn @ Wo + bo (single-pass bf16 MFMA)
    {
        dim3 grid(HIDDEN / 64, M / 128);
        gemm_out_kernel<<<grid, 256, 0, stream>>>(attn, WoT, bo, out);
    }
}

// Round 4
// 177.079 us; speedup vs baseline: 1.2038x; 1.0067x over previous
//
#include <hip/hip_runtime.h>
#include <hip/hip_bf16.h>

#define HIDDEN 1024
#define NH 16
#define BATCH 2
#define SEQ 2048

typedef __attribute__((ext_vector_type(8))) short bf16x8;
typedef __attribute__((ext_vector_type(4))) float f32x4;

__device__ __forceinline__ ushort f2bf(float f) {
    __hip_bfloat16 h = __float2bfloat16(f);
    return *reinterpret_cast<ushort*>(&h);
}
__device__ __forceinline__ float fexp2(float x) {
#if __has_builtin(__builtin_amdgcn_exp2f)
    return __builtin_amdgcn_exp2f(x);
#else
    return exp2f(x);
#endif
}
// pack trunc-bf16(a) low, trunc-bf16(b) high (1 v_perm)
__device__ __forceinline__ uint pack_bf_trunc(float a, float b) {
    return __builtin_amdgcn_perm(__float_as_uint(b), __float_as_uint(a), 0x07060302u);
}

// async global->LDS, 16B per lane
__device__ __forceinline__ void async_copy16(const ushort* g, ushort* l) {
    __builtin_amdgcn_global_load_lds((const __attribute__((address_space(1))) void*)g,
                                     (__attribute__((address_space(3))) void*)l,
                                     16, 0, 0);
}

// ---------------------------------------------------------------------------
// Fused prep: [0,4096) x->bf16 | [4096,7168) Wqkv transpose | [7168,8192) Wo transpose
// ---------------------------------------------------------------------------
__global__ void prep_kernel(const float* __restrict__ x,
                            const float* __restrict__ Wqkv,
                            const float* __restrict__ Wo,
                            ushort* __restrict__ xb,
                            ushort* __restrict__ Wt,
                            ushort* __restrict__ WoT)
{
    __shared__ float t[32][33];
    const int bid = blockIdx.x;
    const int tid = threadIdx.x;

    if (bid < 4096) {
        int i = (bid * 256 + tid) * 4;
        float4 v = *(const float4*)(x + i);
        ushort4 w;
        w.x = f2bf(v.x); w.y = f2bf(v.y); w.z = f2bf(v.z); w.w = f2bf(v.w);
        *(ushort4*)(xb + i) = w;
        return;
    }
    const int r = tid >> 3;
    const int c = (tid & 7) * 4;
    if (bid < 7168) {
        int tt = bid - 4096;
        int k0 = (tt & 31) * 32;
        int n0 = (tt >> 5) * 32;
        const int N = 3 * HIDDEN, K = HIDDEN;
        float4 v = *(const float4*)(Wqkv + (size_t)(k0 + r) * N + n0 + c);
        t[r][c] = v.x; t[r][c + 1] = v.y; t[r][c + 2] = v.z; t[r][c + 3] = v.w;
        __syncthreads();
        ushort4 w;
        w.x = f2bf(t[c + 0][r]); w.y = f2bf(t[c + 1][r]);
        w.z = f2bf(t[c + 2][r]); w.w = f2bf(t[c + 3][r]);
        *(ushort4*)(Wt + (size_t)(n0 + r) * K + k0 + c) = w;
    } else {
        int tt = bid - 7168;
        int k0 = (tt & 31) * 32;
        int n0 = (tt >> 5) * 32;
        const int N = HIDDEN, K = HIDDEN;
        float4 v = *(const float4*)(Wo + (size_t)(k0 + r) * N + n0 + c);
        t[r][c] = v.x; t[r][c + 1] = v.y; t[r][c + 2] = v.z; t[r][c + 3] = v.w;
        __syncthreads();
        ushort4 w;
        w.x = f2bf(t[c + 0][r]); w.y = f2bf(t[c + 1][r]);
        w.z = f2bf(t[c + 2][r]); w.w = f2bf(t[c + 3][r]);
        *(ushort4*)(WoT + (size_t)(n0 + r) * K + k0 + c) = w;
    }
}

// ---------------------------------------------------------------------------
// bf16 MFMA GEMM1: qkv = x @ Wqkv^T + bias -> bf16. Q cols scaled by qscale
// (0.125*log2e -> softmax via exp2). When vt_mode, V cols (>=2048) go
// transposed + Pi-permuted into vtg[b][h][d][s'] (fused transpose_v).
// ---------------------------------------------------------------------------
__global__ __launch_bounds__(256, 3)
void gemm_mfma_bf16_kernel(const ushort* __restrict__ A,
                           const ushort* __restrict__ Bt,
                           const float* __restrict__ bias,
                           ushort* __restrict__ C, int N,
                           int qscale_cols, float qscale,
                           ushort* __restrict__ vtg, int vt_mode)
{
    constexpr int K = 1024;
    __shared__ ushort As[128 * 64];
    __shared__ ushort Bs[128 * 64];

    const int tid  = threadIdx.x;
    const int wave = tid >> 6;
    const int lane = tid & 63;
    const int l16  = lane & 15;
    const int quad = lane >> 4;
    const int wm = wave & 1, wn = wave >> 1;

    const int bm = blockIdx.y * 128;
    const int bn = blockIdx.x * 128;

    const int srow = lane >> 3;
    const int lblk = (lane & 7) ^ srow;
    const ushort* Ag = A  + (size_t)(bm + wave * 32 + srow) * K + lblk * 8;
    const ushort* Bg = Bt + (size_t)(bn + wave * 32 + srow) * K + lblk * 8;
    ushort* Asl = As + wave * 32 * 64;
    ushort* Bsl = Bs + wave * 32 * 64;

    f32x4 acc[4][4];
    #pragma unroll
    for (int i = 0; i < 4; i++)
        #pragma unroll
        for (int j = 0; j < 4; j++) acc[i][j] = (f32x4){0.f, 0.f, 0.f, 0.f};

    for (int k0 = 0; k0 < K; k0 += 64) {
        __syncthreads();
        #pragma unroll
        for (int t = 0; t < 4; t++) {
            async_copy16(Ag + (size_t)t * 8 * K + k0, Asl + t * 8 * 64);
            async_copy16(Bg + (size_t)t * 8 * K + k0, Bsl + t * 8 * 64);
        }
        __syncthreads();

        #pragma unroll
        for (int s = 0; s < 2; s++) {
            bf16x8 af[4], bfr[4];
            #pragma unroll
            for (int i = 0; i < 4; i++) {
                int m = wm * 64 + i * 16 + l16;
                int n = wn * 64 + i * 16 + l16;
                af[i]  = *(const bf16x8*)&As[m * 64 + (((s * 4 + quad) ^ (m & 7)) << 3)];
                bfr[i] = *(const bf16x8*)&Bs[n * 64 + (((s * 4 + quad) ^ (n & 7)) << 3)];
            }
            #pragma unroll
            for (int i = 0; i < 4; i++)
                #pragma unroll
                for (int j = 0; j < 4; j++)
                    acc[i][j] = __builtin_amdgcn_mfma_f32_16x16x32_bf16(af[i], bfr[j], acc[i][j], 0, 0, 0);
        }
    }

    #pragma unroll
    for (int j = 0; j < 4; j++) {
        int col = bn + wn * 64 + j * 16 + l16;
        float bv = bias[col];
        if (vt_mode && col >= 2048) {
            // V -> vtg transposed + Pi: s64 = i*16+quad*4+r; Pi(s64)=(quad*4+r)*4+i
            int dfull = col - 2048;
            int hh = dfull >> 6, dd = dfull & 63;
            int bb = bm >> 11;
            int sb = ((bm & 2047) + wm * 64) >> 6;
            ushort tmp[16];
            #pragma unroll
            for (int i = 0; i < 4; i++)
                #pragma unroll
                for (int r = 0; r < 4; r++)
                    tmp[r * 4 + i] = f2bf(acc[i][j][r] + bv);
            ushort* dst = vtg + ((size_t)((bb * NH + hh) * 64 + dd)) * SEQ
                          + sb * 64 + quad * 16;
            *(uint4*)dst = *(const uint4*)tmp;
            *(uint4*)(dst + 8) = *(const uint4*)(tmp + 8);
        } else {
            float s = (col < qscale_cols) ? qscale : 1.0f;
            #pragma unroll
            for (int i = 0; i < 4; i++) {
                int row0 = bm + wm * 64 + i * 16 + quad * 4;
                #pragma unroll
                for (int r = 0; r < 4; r++)
                    C[(size_t)(row0 + r) * N + col] = f2bf((acc[i][j][r] + bv) * s);
            }
        }
    }
}

// ---------------------------------------------------------------------------
// Output projection, single-pass bf16 MFMA: C[4096][1024]f32 = attn @ WoT^T + bo.
// Tile 128(M)x64(N), BK=64, grid 512 (2+/CU), LDS 24 KB.
// ---------------------------------------------------------------------------
__global__ __launch_bounds__(256, 4)
void gemm_out_kernel(const ushort* __restrict__ A,
                     const ushort* __restrict__ Bt,
                     const float* __restrict__ bias,
                     float* __restrict__ C)
{
    constexpr int K = 1024, N = 1024;
    __shared__ ushort As[128 * 64];
    __shared__ ushort Bs[64 * 64];

    const int tid  = threadIdx.x;
    const int wave = tid >> 6;
    const int lane = tid & 63;
    const int l16  = lane & 15;
    const int quad = lane >> 4;
    const int wm = wave & 1, wn = wave >> 1;

    const int bm = blockIdx.y * 128;
    const int bn = blockIdx.x * 64;

    const int srow = lane >> 3;
    const int lblk = (lane & 7) ^ srow;
    const ushort* Ag = A  + (size_t)(bm + wave * 32 + srow) * K + lblk * 8;
    const ushort* Bg = Bt + (size_t)(bn + wave * 16 + srow) * K + lblk * 8;
    ushort* Asl = As + wave * 32 * 64;
    ushort* Bsl = Bs + wave * 16 * 64;

    f32x4 acc[4][2];
    #pragma unroll
    for (int i = 0; i < 4; i++)
        #pragma unroll
        for (int j = 0; j < 2; j++) acc[i][j] = (f32x4){0.f, 0.f, 0.f, 0.f};

    for (int k0 = 0; k0 < K; k0 += 64) {
        __syncthreads();
        #pragma unroll
        for (int t = 0; t < 4; t++)
            async_copy16(Ag + (size_t)t * 8 * K + k0, Asl + t * 8 * 64);
        #pragma unroll
        for (int t = 0; t < 2; t++)
            async_copy16(Bg + (size_t)t * 8 * K + k0, Bsl + t * 8 * 64);
        __syncthreads();

        #pragma unroll
        for (int s = 0; s < 2; s++) {
            bf16x8 af[4], bfr[2];
            #pragma unroll
            for (int i = 0; i < 4; i++) {
                int m = wm * 64 + i * 16 + l16;
                af[i] = *(const bf16x8*)&As[m * 64 + (((s * 4 + quad) ^ (m & 7)) << 3)];
            }
            #pragma unroll
            for (int j = 0; j < 2; j++) {
                int n = wn * 32 + j * 16 + l16;
                bfr[j] = *(const bf16x8*)&Bs[n * 64 + (((s * 4 + quad) ^ (n & 7)) << 3)];
            }
            #pragma unroll
            for (int i = 0; i < 4; i++)
                #pragma unroll
                for (int j = 0; j < 2; j++)
                    acc[i][j] = __builtin_amdgcn_mfma_f32_16x16x32_bf16(af[i], bfr[j], acc[i][j], 0, 0, 0);
        }
    }

    #pragma unroll
    for (int j = 0; j < 2; j++) {
        int col = bn + wn * 32 + j * 16 + l16;
        float bv = bias[col];
        #pragma unroll
        for (int i = 0; i < 4; i++) {
            int row0 = bm + wm * 64 + i * 16 + quad * 4;
            #pragma unroll
            for (int r = 0; r < 4; r++)
                C[(size_t)(row0 + r) * N + col] = acc[i][j][r] + bv;
        }
    }
}

// ---------------------------------------------------------------------------
// Flash attention v10: LDS-traffic reduction.
// Post-mortem v9: doubling occupancy (8->16 waves/CU) changed nothing ->
// bottleneck is the shared LDS pipe: v9 moved 20 KB/LDS per 16 rows x 64 keys
// = 212 GB/s/CU = ~78% of the 270 GB/s/CU ceiling. v10 amortizes:
//  - 4 waves x 32 q-rows each (mg=2): K-tile reads amortized over 2x rows
//  - PV restructured: ap[2][2] P-frags resident, nt outer loads bv0/bv1 ONCE
//    (v9 read V per row-group) -> 8 V reads/iter instead of 16
//  - per wave-iter: 8K+8V+4P reads + 8 P writes = 24 KB per 32x64
//    (11.7 B/row-key vs v9's 19.5) -> total 1.57 GB, floor ~23 us
// Keeps v9's double-buffer + 1 barrier/iter + XCD swizzle + all layouts.
// ---------------------------------------------------------------------------
__global__ __launch_bounds__(256, 2)
void attn_mfma_v10_kernel(const ushort* __restrict__ qkvb,
                          const ushort* __restrict__ vtg,
                          ushort* __restrict__ attn)
{
    // ushort layout: K[2][4096] | V[2][4096] @8192 | Ps[4][2304] @16384
    // total 25600 ush = 50 KB
    __shared__ __align__(16) ushort smem[25600];

    const int tid  = threadIdx.x;
    const int wave = tid >> 6;
    const int lane = tid & 63;
    const int l16  = lane & 15;
    const int quad = lane >> 4;

    // XCD swizzle: xcd = bid&7 gets heads [xcd*4, xcd*4+4), all 16 qb each.
    const int obid = blockIdx.x;
    const int qb = (obid >> 3) & 15;
    const int bh = (obid & 7) * 4 + (obid >> 7);
    const int h  = bh & (NH - 1);
    const int b  = bh >> 4;

    const int qbase = qb * 128 + wave * 32;   // 32 q-rows per wave
    const int hoff  = h * 64;

    ushort* Psw = smem + 16384 + wave * 2304;

    // Q fragments: 2 row-groups of 16
    bf16x8 a_q[2][2];
    #pragma unroll
    for (int mg = 0; mg < 2; mg++) {
        int qrow = b * SEQ + qbase + mg * 16 + l16;
        const ushort* qp = qkvb + (size_t)qrow * 3072 + hoff + quad * 8;
        a_q[mg][0] = *(const bf16x8*)qp;
        a_q[mg][1] = *(const bf16x8*)(qp + 32);
    }

    f32x4 o[2][4];
    f32x4 lacc[2];
    #pragma unroll
    for (int mg = 0; mg < 2; mg++) {
        lacc[mg] = (f32x4){0.f, 0.f, 0.f, 0.f};
        #pragma unroll
        for (int nt = 0; nt < 4; nt++) o[mg][nt] = (f32x4){0.f, 0.f, 0.f, 0.f};
    }

    bf16x8 b_ones;
    #pragma unroll
    for (int j = 0; j < 8; j++) b_ones[j] = (short)0x3f80;

    const ushort* kvb    = qkvb + (size_t)b * SEQ * 3072;
    const ushort* vtg_bh = vtg + (size_t)((b * NH + h) * 64) * SEQ;

    // staging: 256 thr x 2 calls x 16B per array = 8 KB = one 64x64 tile.
    // wave covers 16 rows of K and 16 rows (d) of V: rows wave*16 + c*8 + srow8.
    // global col pre-swizzled so linear LDS dest yields XOR-swizzled layout.
    const int srow8 = lane >> 3;
    const int gblk  = ((lane & 7) ^ srow8) << 3;
    const ushort* kg = kvb + (size_t)(wave * 16 + srow8) * 3072 + 1024 + hoff + gblk;
    const ushort* vg = vtg_bh + (size_t)(wave * 16 + srow8) * SEQ + gblk;

    ushort* k_dst = smem + wave * 1024;          // + c*512 + (cur<<12)
    ushort* v_dst = smem + 8192 + wave * 1024;   // + c*512 + (cur<<12)

    // prologue: stage tile 0 into buf 0; barrier drains vmcnt
    #pragma unroll
    for (int c = 0; c < 2; c++) {
        async_copy16(kg + (size_t)(c * 8) * 3072, k_dst + c * 512);
        async_copy16(vg + (size_t)(c * 8) * SEQ,  v_dst + c * 512);
    }
    __syncthreads();

    int cur = 0;
    for (int t = 0; t < 32; t++) {
        // stage tile t+1 into the other buffer (no drain here; the barrier
        // at the end of this iter performs the vmcnt(0) drain after ~1000cy)
        if (t < 31) {
            const int k0n = (t + 1) * 64;
            #pragma unroll
            for (int c = 0; c < 2; c++) {
                async_copy16(kg + (size_t)(k0n + c * 8) * 3072,
                             k_dst + c * 512 + ((cur ^ 1) << 12));
                async_copy16(vg + (size_t)(c * 8) * SEQ + k0n,
                             v_dst + c * 512 + ((cur ^ 1) << 12));
            }
        }
        const ushort* Ks = smem + (cur << 12);
        const ushort* Vs = smem + 8192 + (cur << 12);

        // QK^T: load each K fragment once, use for both row-groups
        f32x4 sc[2][4];
        #pragma unroll
        for (int nt = 0; nt < 4; nt++) {
            int key = nt * 16 + l16;
            bf16x8 bk0 = *(const bf16x8*)&Ks[key * 64 + ((quad ^ (key & 7)) << 3)];
            bf16x8 bk1 = *(const bf16x8*)&Ks[key * 64 + (((4 + quad) ^ (key & 7)) << 3)];
            #pragma unroll
            for (int mg = 0; mg < 2; mg++) {
                f32x4 a = (f32x4){0.f, 0.f, 0.f, 0.f};
                a = __builtin_amdgcn_mfma_f32_16x16x32_bf16(a_q[mg][0], bk0, a, 0, 0, 0);
                a = __builtin_amdgcn_mfma_f32_16x16x32_bf16(a_q[mg][1], bk1, a, 0, 0, 0);
                sc[mg][nt] = a;
            }
        }

        // softmax (exp2, Q pre-scaled) -> Pi-packed trunc-bf16 P rows in LDS
        #pragma unroll
        for (int mg = 0; mg < 2; mg++) {
            #pragma unroll
            for (int r = 0; r < 4; r++) {
                int q = mg * 16 + quad * 4 + r;
                uint2 pk2;
                pk2.x = pack_bf_trunc(fexp2(sc[mg][0][r]), fexp2(sc[mg][1][r]));
                pk2.y = pack_bf_trunc(fexp2(sc[mg][2][r]), fexp2(sc[mg][3][r]));
                *(uint2*)&Psw[q * 72 + l16 * 4] = pk2;
            }
        }

        asm volatile("s_waitcnt lgkmcnt(0)" ::: "memory");

        // PV: P-frags resident; each V fragment loaded once, used by both mg
        bf16x8 ap[2][2];
        #pragma unroll
        for (int mg = 0; mg < 2; mg++) {
            ap[mg][0] = *(const bf16x8*)&Psw[(mg * 16 + l16) * 72 + quad * 8];
            ap[mg][1] = *(const bf16x8*)&Psw[(mg * 16 + l16) * 72 + 32 + quad * 8];
        }
        #pragma unroll
        for (int nt = 0; nt < 4; nt++) {
            int d = nt * 16 + l16;
            bf16x8 bv0 = *(const bf16x8*)&Vs[d * 64 + ((quad ^ (d & 7)) << 3)];
            bf16x8 bv1 = *(const bf16x8*)&Vs[d * 64 + (((4 + quad) ^ (d & 7)) << 3)];
            #pragma unroll
            for (int mg = 0; mg < 2; mg++) {
                o[mg][nt] = __builtin_amdgcn_mfma_f32_16x16x32_bf16(ap[mg][0], bv0, o[mg][nt], 0, 0, 0);
                o[mg][nt] = __builtin_amdgcn_mfma_f32_16x16x32_bf16(ap[mg][1], bv1, o[mg][nt], 0, 0, 0);
            }
        }
        #pragma unroll
        for (int mg = 0; mg < 2; mg++) {
            lacc[mg] = __builtin_amdgcn_mfma_f32_16x16x32_bf16(ap[mg][0], b_ones, lacc[mg], 0, 0, 0);
            lacc[mg] = __builtin_amdgcn_mfma_f32_16x16x32_bf16(ap[mg][1], b_ones, lacc[mg], 0, 0, 0);
        }

        // everyone done reading buf[cur]; tile t+1 loads drained by barrier
        __syncthreads();
        cur ^= 1;
    }

    // epilogue: per-wave, no cross-wave combine
    #pragma unroll
    for (int mg = 0; mg < 2; mg++) {
        #pragma unroll
        for (int r = 0; r < 4; r++) {
            float inv = 1.f / lacc[mg][r];
            int row = b * SEQ + qbase + mg * 16 + quad * 4 + r;
            size_t base = (size_t)row * HIDDEN + hoff + l16;
            #pragma unroll
            for (int nt = 0; nt < 4; nt++)
                attn[base + nt * 16] = f2bf(o[mg][nt][r] * inv);
        }
    }
}

// ---------------------------------------------------------------------------
// Fallback attention (no vtg workspace): barrier kernel staging K + Pi-V.
// ---------------------------------------------------------------------------
__global__ __launch_bounds__(512, 4)
void attn_mfma_fb_kernel(const ushort* __restrict__ qkvb,
                         ushort* __restrict__ attn)
{
    __shared__ __align__(16) ushort smem[34816];

    const int tid   = threadIdx.x;
    const int wave  = tid >> 6;
    const int wavel = wave & 3;
    const int kh    = wave >> 2;
    const int lane  = tid & 63;
    const int l16   = lane & 15;
    const int quad  = lane >> 4;

    const int qb = blockIdx.x & 15;
    const int bh = blockIdx.x >> 4;
    const int h  = bh & (NH - 1);
    const int b  = bh >> 4;

    const int qbase = qb * 128;
    const int hoff  = h * 64;

    ushort* KsH = smem + kh * 4096;
    ushort* VsH = smem + 8192 + kh * 4096;
    ushort* Psw = smem + 16384 + wave * 2304;

    bf16x8 a_q[2][2];
    #pragma unroll
    for (int mg = 0; mg < 2; mg++) {
        int qrow = b * SEQ + qbase + wavel * 32 + mg * 16 + l16;
        const ushort* qp = qkvb + (size_t)qrow * 3072 + hoff + quad * 8;
        a_q[mg][0] = *(const bf16x8*)qp;
        a_q[mg][1] = *(const bf16x8*)(qp + 32);
    }

    f32x4 o[2][4];
    f32x4 lacc[2];
    #pragma unroll
    for (int mg = 0; mg < 2; mg++) {
        lacc[mg] = (f32x4){0.f, 0.f, 0.f, 0.f};
        #pragma unroll
        for (int nt = 0; nt < 4; nt++) o[mg][nt] = (f32x4){0.f, 0.f, 0.f, 0.f};
    }

    bf16x8 b_ones;
    #pragma unroll
    for (int j = 0; j < 8; j++) b_ones[j] = (short)0x3f80;

    const ushort* kvb = qkvb + (size_t)b * SEQ * 3072;

    for (int t = 0; t < 16; t++) {
        const int k0 = t * 64;
        __syncthreads();
        {
            const int tl = tid & 255;
            #pragma unroll
            for (int i = 0; i < 2; i++) {
                int key = (tl >> 3) + 32 * i;
                int blk = tl & 7;
                const ushort* ksrc = kvb + (size_t)(kh * 1024 + k0 + key) * 3072 + 1024 + hoff + blk * 8;
                uint4 kv = *(const uint4*)ksrc;
                *(uint4*)&KsH[key * 64 + ((blk ^ (key & 7)) << 3)] = kv;
                uint4 vv = *(const uint4*)(ksrc + 1024);
                const ushort* vpp = (const ushort*)&vv;
                int pk_ = (key & 15) * 4 + (key >> 4);
                #pragma unroll
                for (int j = 0; j < 8; j++) {
                    int d = blk * 8 + j;
                    VsH[d * 64 + (((pk_ >> 3) ^ (d & 7)) << 3) + (pk_ & 7)] = vpp[j];
                }
            }
        }
        __syncthreads();

        f32x4 sc[2][4];
        #pragma unroll
        for (int nt = 0; nt < 4; nt++) {
            int key = nt * 16 + l16;
            bf16x8 bk0 = *(const bf16x8*)&KsH[key * 64 + ((quad ^ (key & 7)) << 3)];
            bf16x8 bk1 = *(const bf16x8*)&KsH[key * 64 + (((4 + quad) ^ (key & 7)) << 3)];
            #pragma unroll
            for (int mg = 0; mg < 2; mg++) {
                f32x4 a = (f32x4){0.f, 0.f, 0.f, 0.f};
                a = __builtin_amdgcn_mfma_f32_16x16x32_bf16(a_q[mg][0], bk0, a, 0, 0, 0);
                a = __builtin_amdgcn_mfma_f32_16x16x32_bf16(a_q[mg][1], bk1, a, 0, 0, 0);
                sc[mg][nt] = a;
            }
        }

        #pragma unroll
        for (int mg = 0; mg < 2; mg++) {
            #pragma unroll
            for (int r = 0; r < 4; r++) {
                int q = mg * 16 + quad * 4 + r;
                uint2 pk2;
                pk2.x = pack_bf_trunc(fexp2(sc[mg][0][r]), fexp2(sc[mg][1][r]));
                pk2.y = pack_bf_trunc(fexp2(sc[mg][2][r]), fexp2(sc[mg][3][r]));
                *(uint2*)&Psw[q * 72 + l16 * 4] = pk2;
            }
        }

        asm volatile("s_waitcnt lgkmcnt(0)" ::: "memory");
        bf16x8 a_p[2][2];
        #pragma unroll
        for (int mg = 0; mg < 2; mg++) {
            a_p[mg][0] = *(const bf16x8*)&Psw[(mg * 16 + l16) * 72 + quad * 8];
            a_p[mg][1] = *(const bf16x8*)&Psw[(mg * 16 + l16) * 72 + 32 + quad * 8];
        }

        #pragma unroll
        for (int nt = 0; nt < 4; nt++) {
            int d = nt * 16 + l16;
            bf16x8 bv0 = *(const bf16x8*)&VsH[d * 64 + ((quad ^ (d & 7)) << 3)];
            bf16x8 bv1 = *(const bf16x8*)&VsH[d * 64 + (((4 + quad) ^ (d & 7)) << 3)];
            #pragma unroll
            for (int mg = 0; mg < 2; mg++) {
                o[mg][nt] = __builtin_amdgcn_mfma_f32_16x16x32_bf16(a_p[mg][0], bv0, o[mg][nt], 0, 0, 0);
                o[mg][nt] = __builtin_amdgcn_mfma_f32_16x16x32_bf16(a_p[mg][1], bv1, o[mg][nt], 0, 0, 0);
            }
        }
        #pragma unroll
        for (int mg = 0; mg < 2; mg++) {
            lacc[mg] = __builtin_amdgcn_mfma_f32_16x16x32_bf16(a_p[mg][0], b_ones, lacc[mg], 0, 0, 0);
            lacc[mg] = __builtin_amdgcn_mfma_f32_16x16x32_bf16(a_p[mg][1], b_ones, lacc[mg], 0, 0, 0);
        }
    }

    __syncthreads();
    float* osc = (float*)smem;
    float* lsc = (float*)(smem + 16384);
    const int fo = wavel * 2048 + quad * 64 + l16 * 4;
    const int fl = wavel * 512 + quad * 64 + l16 * 4;
    if (kh == 1) {
        #pragma unroll
        for (int mg = 0; mg < 2; mg++) {
            #pragma unroll
            for (int nt = 0; nt < 4; nt++)
                *(f32x4*)&osc[fo + (mg * 4 + nt) * 256] = o[mg][nt];
            *(f32x4*)&lsc[fl + mg * 256] = lacc[mg];
        }
    }
    __syncthreads();
    if (kh == 0) {
        #pragma unroll
        for (int mg = 0; mg < 2; mg++) {
            #pragma unroll
            for (int nt = 0; nt < 4; nt++)
                o[mg][nt] += *(const f32x4*)&osc[fo + (mg * 4 + nt) * 256];
            lacc[mg] += *(const f32x4*)&lsc[fl + mg * 256];
        }
        #pragma unroll
        for (int mg = 0; mg < 2; mg++) {
            #pragma unroll
            for (int r = 0; r < 4; r++) {
                float inv = 1.f / lacc[mg][r];
                int row = b * SEQ + qbase + wavel * 32 + mg * 16 + quad * 4 + r;
                size_t base = (size_t)row * HIDDEN + hoff + l16;
                #pragma unroll
                for (int nt = 0; nt < 4; nt++)
                    attn[base + nt * 16] = f2bf(o[mg][nt][r] * inv);
            }
        }
    }
}

extern "C" void kernel_launch(void* const* d_in, const int* in_sizes, int n_in,
                              void* d_out, int out_size, void* d_ws, size_t ws_size,
                              hipStream_t stream) {
    const float* x    = (const float*)d_in[0];
    const float* Wqkv = (const float*)d_in[1];
    const float* bqkv = (const float*)d_in[2];
    const float* Wo   = (const float*)d_in[3];
    const float* bo   = (const float*)d_in[4];
    float* out = (float*)d_out;

    const int M = BATCH * SEQ;                   // 4096
    const size_t MB = 1024 * 1024;

    // workspace (48 MB):
    //   [0,24) qkvb | [24,32) attn (xb overlaps: prep/GEMM1 only)
    //   [32,38) Wt (prep/GEMM1) | [38,40) WoT (prep->GEMM3) | [40,48) vtg
    char* ws = (char*)d_ws;
    ushort* qkvb = (ushort*)ws;
    ushort* attn = (ushort*)(ws + 24 * MB);
    ushort* xb   = (ushort*)(ws + 24 * MB);
    ushort* Wt   = (ushort*)(ws + 32 * MB);
    ushort* WoT  = (ushort*)(ws + 38 * MB);
    ushort* vtg  = (ushort*)(ws + 40 * MB);
    const int use_vtg = (ws_size >= 48 * MB) ? 1 : 0;

    const float qscale = 0.125f * 1.44269504088896f;   // fold log2e -> exp2 softmax

    // 0) fused preps (x->bf16, Wqkv transpose, Wo transpose)
    prep_kernel<<<8192, 256, 0, stream>>>(x, Wqkv, Wo, xb, Wt, WoT);

    // 1) qkv = (x @ Wqkv + bqkv) -> bf16; V written transposed to vtg when able
    {
        dim3 grid((3 * HIDDEN) / 128, M / 128);
        gemm_mfma_bf16_kernel<<<grid, 256, 0, stream>>>(xb, Wt, bqkv, qkvb,
                                                        3 * HIDDEN, HIDDEN, qscale,
                                                        vtg, use_vtg);
    }

    // 2) flash attention -> attn bf16
    if (use_vtg) {
        attn_mfma_v10_kernel<<<BATCH * NH * (SEQ / 128), 256, 0, stream>>>(
            qkvb, vtg, attn);
    } else {
        attn_mfma_fb_kernel<<<BATCH * NH * (SEQ / 128), 512, 0, stream>>>(
            qkvb, attn);
    }

    // 3) out = attn @ Wo + bo (single-pass bf16 MFMA)
    {
        dim3 grid(HIDDEN / 64, M / 128);
        gemm_out_kernel<<<grid, 256, 0, stream>>>(attn, WoT, bo, out);
    }
}

// Round 6
// 174.248 us; speedup vs baseline: 1.2234x; 1.0163x over previous
//
#include <hip/hip_runtime.h>
#include <hip/hip_bf16.h>

#define HIDDEN 1024
#define NH 16
#define BATCH 2
#define SEQ 2048

typedef __attribute__((ext_vector_type(8))) short bf16x8;
typedef __attribute__((ext_vector_type(4))) float f32x4;
typedef __attribute__((ext_vector_type(2))) uint uint2v;

__device__ __forceinline__ ushort f2bf(float f) {
    __hip_bfloat16 h = __float2bfloat16(f);
    return *reinterpret_cast<ushort*>(&h);
}
__device__ __forceinline__ float fexp2(float x) {
#if __has_builtin(__builtin_amdgcn_exp2f)
    return __builtin_amdgcn_exp2f(x);
#else
    return exp2f(x);
#endif
}
// pack trunc-bf16(a) low, trunc-bf16(b) high (1 v_perm)
__device__ __forceinline__ uint pack_bf_trunc(float a, float b) {
    return __builtin_amdgcn_perm(__float_as_uint(b), __float_as_uint(a), 0x07060302u);
}

// butterfly: (A,B) -> A' = [a0,b0,a1,b1], B' = [a2,b2,a3,b3] (16-lane rows).
// = permlane16_swap (odd rows of A <-> even rows of B) then permlane32_swap
// (upper half of A <-> lower half of B).
__device__ __forceinline__ void bfly(uint &a, uint &b) {
#if __has_builtin(__builtin_amdgcn_permlane16_swap)
    uint2v t = __builtin_amdgcn_permlane16_swap(a, b, false, false);
    uint2v s = __builtin_amdgcn_permlane32_swap(t[0], t[1], false, false);
    a = s[0]; b = s[1];
#else
    asm volatile("v_permlane16_swap_b32 %0, %1" : "+v"(a), "+v"(b));
    asm volatile("v_permlane32_swap_b32 %0, %1" : "+v"(a), "+v"(b));
#endif
}

// async global->LDS, 16B per lane
__device__ __forceinline__ void async_copy16(const ushort* g, ushort* l) {
    __builtin_amdgcn_global_load_lds((const __attribute__((address_space(1))) void*)g,
                                     (__attribute__((address_space(3))) void*)l,
                                     16, 0, 0);
}

// ---------------------------------------------------------------------------
// Fused prep: [0,4096) x->bf16 | [4096,7168) Wqkv transpose | [7168,8192) Wo transpose
// ---------------------------------------------------------------------------
__global__ void prep_kernel(const float* __restrict__ x,
                            const float* __restrict__ Wqkv,
                            const float* __restrict__ Wo,
                            ushort* __restrict__ xb,
                            ushort* __restrict__ Wt,
                            ushort* __restrict__ WoT)
{
    __shared__ float t[32][33];
    const int bid = blockIdx.x;
    const int tid = threadIdx.x;

    if (bid < 4096) {
        int i = (bid * 256 + tid) * 4;
        float4 v = *(const float4*)(x + i);
        ushort4 w;
        w.x = f2bf(v.x); w.y = f2bf(v.y); w.z = f2bf(v.z); w.w = f2bf(v.w);
        *(ushort4*)(xb + i) = w;
        return;
    }
    const int r = tid >> 3;
    const int c = (tid & 7) * 4;
    if (bid < 7168) {
        int tt = bid - 4096;
        int k0 = (tt & 31) * 32;
        int n0 = (tt >> 5) * 32;
        const int N = 3 * HIDDEN, K = HIDDEN;
        float4 v = *(const float4*)(Wqkv + (size_t)(k0 + r) * N + n0 + c);
        t[r][c] = v.x; t[r][c + 1] = v.y; t[r][c + 2] = v.z; t[r][c + 3] = v.w;
        __syncthreads();
        ushort4 w;
        w.x = f2bf(t[c + 0][r]); w.y = f2bf(t[c + 1][r]);
        w.z = f2bf(t[c + 2][r]); w.w = f2bf(t[c + 3][r]);
        *(ushort4*)(Wt + (size_t)(n0 + r) * K + k0 + c) = w;
    } else {
        int tt = bid - 7168;
        int k0 = (tt & 31) * 32;
        int n0 = (tt >> 5) * 32;
        const int N = HIDDEN, K = HIDDEN;
        float4 v = *(const float4*)(Wo + (size_t)(k0 + r) * N + n0 + c);
        t[r][c] = v.x; t[r][c + 1] = v.y; t[r][c + 2] = v.z; t[r][c + 3] = v.w;
        __syncthreads();
        ushort4 w;
        w.x = f2bf(t[c + 0][r]); w.y = f2bf(t[c + 1][r]);
        w.z = f2bf(t[c + 2][r]); w.w = f2bf(t[c + 3][r]);
        *(ushort4*)(WoT + (size_t)(n0 + r) * K + k0 + c) = w;
    }
}

// ---------------------------------------------------------------------------
// bf16 MFMA GEMM1: qkv = x @ Wqkv^T + bias -> bf16. Q cols scaled by qscale
// (0.125*log2e -> softmax via exp2). When vt_mode, V cols (>=2048) go
// transposed + Pi-permuted into vtg[b][h][d][s'] (fused transpose_v).
// ---------------------------------------------------------------------------
__global__ __launch_bounds__(256, 3)
void gemm_mfma_bf16_kernel(const ushort* __restrict__ A,
                           const ushort* __restrict__ Bt,
                           const float* __restrict__ bias,
                           ushort* __restrict__ C, int N,
                           int qscale_cols, float qscale,
                           ushort* __restrict__ vtg, int vt_mode)
{
    constexpr int K = 1024;
    __shared__ ushort As[128 * 64];
    __shared__ ushort Bs[128 * 64];

    const int tid  = threadIdx.x;
    const int wave = tid >> 6;
    const int lane = tid & 63;
    const int l16  = lane & 15;
    const int quad = lane >> 4;
    const int wm = wave & 1, wn = wave >> 1;

    const int bm = blockIdx.y * 128;
    const int bn = blockIdx.x * 128;

    const int srow = lane >> 3;
    const int lblk = (lane & 7) ^ srow;
    const ushort* Ag = A  + (size_t)(bm + wave * 32 + srow) * K + lblk * 8;
    const ushort* Bg = Bt + (size_t)(bn + wave * 32 + srow) * K + lblk * 8;
    ushort* Asl = As + wave * 32 * 64;
    ushort* Bsl = Bs + wave * 32 * 64;

    f32x4 acc[4][4];
    #pragma unroll
    for (int i = 0; i < 4; i++)
        #pragma unroll
        for (int j = 0; j < 4; j++) acc[i][j] = (f32x4){0.f, 0.f, 0.f, 0.f};

    for (int k0 = 0; k0 < K; k0 += 64) {
        __syncthreads();
        #pragma unroll
        for (int t = 0; t < 4; t++) {
            async_copy16(Ag + (size_t)t * 8 * K + k0, Asl + t * 8 * 64);
            async_copy16(Bg + (size_t)t * 8 * K + k0, Bsl + t * 8 * 64);
        }
        __syncthreads();

        #pragma unroll
        for (int s = 0; s < 2; s++) {
            bf16x8 af[4], bfr[4];
            #pragma unroll
            for (int i = 0; i < 4; i++) {
                int m = wm * 64 + i * 16 + l16;
                int n = wn * 64 + i * 16 + l16;
                af[i]  = *(const bf16x8*)&As[m * 64 + (((s * 4 + quad) ^ (m & 7)) << 3)];
                bfr[i] = *(const bf16x8*)&Bs[n * 64 + (((s * 4 + quad) ^ (n & 7)) << 3)];
            }
            #pragma unroll
            for (int i = 0; i < 4; i++)
                #pragma unroll
                for (int j = 0; j < 4; j++)
                    acc[i][j] = __builtin_amdgcn_mfma_f32_16x16x32_bf16(af[i], bfr[j], acc[i][j], 0, 0, 0);
        }
    }

    #pragma unroll
    for (int j = 0; j < 4; j++) {
        int col = bn + wn * 64 + j * 16 + l16;
        float bv = bias[col];
        if (vt_mode && col >= 2048) {
            // V -> vtg transposed + Pi: s64 = i*16+quad*4+r; Pi(s64)=(quad*4+r)*4+i
            int dfull = col - 2048;
            int hh = dfull >> 6, dd = dfull & 63;
            int bb = bm >> 11;
            int sb = ((bm & 2047) + wm * 64) >> 6;
            ushort tmp[16];
            #pragma unroll
            for (int i = 0; i < 4; i++)
                #pragma unroll
                for (int r = 0; r < 4; r++)
                    tmp[r * 4 + i] = f2bf(acc[i][j][r] + bv);
            ushort* dst = vtg + ((size_t)((bb * NH + hh) * 64 + dd)) * SEQ
                          + sb * 64 + quad * 16;
            *(uint4*)dst = *(const uint4*)tmp;
            *(uint4*)(dst + 8) = *(const uint4*)(tmp + 8);
        } else {
            float s = (col < qscale_cols) ? qscale : 1.0f;
            #pragma unroll
            for (int i = 0; i < 4; i++) {
                int row0 = bm + wm * 64 + i * 16 + quad * 4;
                #pragma unroll
                for (int r = 0; r < 4; r++)
                    C[(size_t)(row0 + r) * N + col] = f2bf((acc[i][j][r] + bv) * s);
            }
        }
    }
}

// ---------------------------------------------------------------------------
// Output projection, single-pass bf16 MFMA: C[4096][1024]f32 = attn @ WoT^T + bo.
// Tile 128(M)x64(N), BK=64, grid 512 (2+/CU), LDS 24 KB.
// ---------------------------------------------------------------------------
__global__ __launch_bounds__(256, 4)
void gemm_out_kernel(const ushort* __restrict__ A,
                     const ushort* __restrict__ Bt,
                     const float* __restrict__ bias,
                     float* __restrict__ C)
{
    constexpr int K = 1024, N = 1024;
    __shared__ ushort As[128 * 64];
    __shared__ ushort Bs[64 * 64];

    const int tid  = threadIdx.x;
    const int wave = tid >> 6;
    const int lane = tid & 63;
    const int l16  = lane & 15;
    const int quad = lane >> 4;
    const int wm = wave & 1, wn = wave >> 1;

    const int bm = blockIdx.y * 128;
    const int bn = blockIdx.x * 64;

    const int srow = lane >> 3;
    const int lblk = (lane & 7) ^ srow;
    const ushort* Ag = A  + (size_t)(bm + wave * 32 + srow) * K + lblk * 8;
    const ushort* Bg = Bt + (size_t)(bn + wave * 16 + srow) * K + lblk * 8;
    ushort* Asl = As + wave * 32 * 64;
    ushort* Bsl = Bs + wave * 16 * 64;

    f32x4 acc[4][2];
    #pragma unroll
    for (int i = 0; i < 4; i++)
        #pragma unroll
        for (int j = 0; j < 2; j++) acc[i][j] = (f32x4){0.f, 0.f, 0.f, 0.f};

    for (int k0 = 0; k0 < K; k0 += 64) {
        __syncthreads();
        #pragma unroll
        for (int t = 0; t < 4; t++)
            async_copy16(Ag + (size_t)t * 8 * K + k0, Asl + t * 8 * 64);
        #pragma unroll
        for (int t = 0; t < 2; t++)
            async_copy16(Bg + (size_t)t * 8 * K + k0, Bsl + t * 8 * 64);
        __syncthreads();

        #pragma unroll
        for (int s = 0; s < 2; s++) {
            bf16x8 af[4], bfr[2];
            #pragma unroll
            for (int i = 0; i < 4; i++) {
                int m = wm * 64 + i * 16 + l16;
                af[i] = *(const bf16x8*)&As[m * 64 + (((s * 4 + quad) ^ (m & 7)) << 3)];
            }
            #pragma unroll
            for (int j = 0; j < 2; j++) {
                int n = wn * 32 + j * 16 + l16;
                bfr[j] = *(const bf16x8*)&Bs[n * 64 + (((s * 4 + quad) ^ (n & 7)) << 3)];
            }
            #pragma unroll
            for (int i = 0; i < 4; i++)
                #pragma unroll
                for (int j = 0; j < 2; j++)
                    acc[i][j] = __builtin_amdgcn_mfma_f32_16x16x32_bf16(af[i], bfr[j], acc[i][j], 0, 0, 0);
        }
    }

    #pragma unroll
    for (int j = 0; j < 2; j++) {
        int col = bn + wn * 32 + j * 16 + l16;
        float bv = bias[col];
        #pragma unroll
        for (int i = 0; i < 4; i++) {
            int row0 = bm + wm * 64 + i * 16 + quad * 4;
            #pragma unroll
            for (int r = 0; r < 4; r++)
                C[(size_t)(row0 + r) * N + col] = acc[i][j][r] + bv;
        }
    }
}

// ---------------------------------------------------------------------------
// Flash attention v12: in-register softmax via swapped QK^T (corrected v11).
// mfma(K,Q) puts P lane-local: lane (l16,quad) reg r holds
// P[q=l16][key = nt*16 + quad*4 + r]. With the Pi layout (s'=u*4+i <->
// key=i*16+u), the PV A-fragment uint j pairs nt0/nt1 (or nt2/nt3) values:
// pack sc[0][r] with sc[1][r] (w0) and sc[2][r] with sc[3][r] (w1), then
// butterfly pairs (w0[0],w0[2]) (w0[1],w0[3]) (w1[0],w1[2]) (w1[1],w1[3]):
// permlane16_swap THEN permlane32_swap gives A'=[a0,b0,a1,b1] -> ap0 slot,
// B'=[a2,b2,a3,b3] -> ap1 slot. (v11 had pairing and order wrong.)
// Eliminates P LDS (51.2 -> 32 KB), removes the per-iter lgkm round-trip.
// ---------------------------------------------------------------------------
__global__ __launch_bounds__(256, 2)
void attn_mfma_v12_kernel(const ushort* __restrict__ qkvb,
                          const ushort* __restrict__ vtg,
                          ushort* __restrict__ attn)
{
    // ushort layout: K[2][4096] | V[2][4096] @8192  -> 32 KB
    __shared__ __align__(16) ushort smem[16384];

    const int tid  = threadIdx.x;
    const int wave = tid >> 6;
    const int lane = tid & 63;
    const int l16  = lane & 15;
    const int quad = lane >> 4;

    // XCD swizzle: xcd = bid&7 gets heads [xcd*4, xcd*4+4), all 16 qb each.
    const int obid = blockIdx.x;
    const int qb = (obid >> 3) & 15;
    const int bh = (obid & 7) * 4 + (obid >> 7);
    const int h  = bh & (NH - 1);
    const int b  = bh >> 4;

    const int qbase = qb * 128 + wave * 32;   // 32 q-rows per wave
    const int hoff  = h * 64;

    // Q fragments: 2 row-groups of 16 (used as the MFMA *B* operand)
    bf16x8 a_q[2][2];
    #pragma unroll
    for (int mg = 0; mg < 2; mg++) {
        int qrow = b * SEQ + qbase + mg * 16 + l16;
        const ushort* qp = qkvb + (size_t)qrow * 3072 + hoff + quad * 8;
        a_q[mg][0] = *(const bf16x8*)qp;
        a_q[mg][1] = *(const bf16x8*)(qp + 32);
    }

    f32x4 o[2][4];
    f32x4 lacc[2];
    #pragma unroll
    for (int mg = 0; mg < 2; mg++) {
        lacc[mg] = (f32x4){0.f, 0.f, 0.f, 0.f};
        #pragma unroll
        for (int nt = 0; nt < 4; nt++) o[mg][nt] = (f32x4){0.f, 0.f, 0.f, 0.f};
    }

    bf16x8 b_ones;
    #pragma unroll
    for (int j = 0; j < 8; j++) b_ones[j] = (short)0x3f80;

    const ushort* kvb    = qkvb + (size_t)b * SEQ * 3072;
    const ushort* vtg_bh = vtg + (size_t)((b * NH + h) * 64) * SEQ;

    // staging: 256 thr x 2 calls x 16B per array = 8 KB = one 64x64 tile.
    // global col pre-swizzled so linear LDS dest yields XOR-swizzled layout.
    const int srow8 = lane >> 3;
    const int gblk  = ((lane & 7) ^ srow8) << 3;
    const ushort* kg = kvb + (size_t)(wave * 16 + srow8) * 3072 + 1024 + hoff + gblk;
    const ushort* vg = vtg_bh + (size_t)(wave * 16 + srow8) * SEQ + gblk;

    ushort* k_dst = smem + wave * 1024;          // + c*512 + (cur<<12)
    ushort* v_dst = smem + 8192 + wave * 1024;   // + c*512 + (cur<<12)

    // prologue: stage tile 0 into buf 0; barrier drains vmcnt
    #pragma unroll
    for (int c = 0; c < 2; c++) {
        async_copy16(kg + (size_t)(c * 8) * 3072, k_dst + c * 512);
        async_copy16(vg + (size_t)(c * 8) * SEQ,  v_dst + c * 512);
    }
    __syncthreads();

    int cur = 0;
    for (int t = 0; t < 32; t++) {
        // stage tile t+1 into the other buffer (drained by end-of-iter barrier)
        if (t < 31) {
            const int k0n = (t + 1) * 64;
            #pragma unroll
            for (int c = 0; c < 2; c++) {
                async_copy16(kg + (size_t)(k0n + c * 8) * 3072,
                             k_dst + c * 512 + ((cur ^ 1) << 12));
                async_copy16(vg + (size_t)(c * 8) * SEQ + k0n,
                             v_dst + c * 512 + ((cur ^ 1) << 12));
            }
        }
        const ushort* Ks = smem + (cur << 12);
        const ushort* Vs = smem + 8192 + (cur << 12);

        // swapped QK^T: D[row=key-in-tile=quad*4+r][col=q=l16].
        f32x4 sc[2][4];
        __builtin_amdgcn_s_setprio(1);
        #pragma unroll
        for (int nt = 0; nt < 4; nt++) {
            int key = nt * 16 + l16;
            bf16x8 bk0 = *(const bf16x8*)&Ks[key * 64 + ((quad ^ (key & 7)) << 3)];
            bf16x8 bk1 = *(const bf16x8*)&Ks[key * 64 + (((4 + quad) ^ (key & 7)) << 3)];
            #pragma unroll
            for (int mg = 0; mg < 2; mg++) {
                f32x4 a = (f32x4){0.f, 0.f, 0.f, 0.f};
                a = __builtin_amdgcn_mfma_f32_16x16x32_bf16(bk0, a_q[mg][0], a, 0, 0, 0);
                a = __builtin_amdgcn_mfma_f32_16x16x32_bf16(bk1, a_q[mg][1], a, 0, 0, 0);
                sc[mg][nt] = a;
            }
        }
        __builtin_amdgcn_s_setprio(0);

        // exp2 + pack (nt0 with nt1, nt2 with nt3) + butterfly -> PV frags.
        bf16x8 ap[2][2];
        #pragma unroll
        for (int mg = 0; mg < 2; mg++) {
            uint w00 = pack_bf_trunc(fexp2(sc[mg][0][0]), fexp2(sc[mg][1][0]));
            uint w01 = pack_bf_trunc(fexp2(sc[mg][0][1]), fexp2(sc[mg][1][1]));
            uint w02 = pack_bf_trunc(fexp2(sc[mg][0][2]), fexp2(sc[mg][1][2]));
            uint w03 = pack_bf_trunc(fexp2(sc[mg][0][3]), fexp2(sc[mg][1][3]));
            uint w10 = pack_bf_trunc(fexp2(sc[mg][2][0]), fexp2(sc[mg][3][0]));
            uint w11 = pack_bf_trunc(fexp2(sc[mg][2][1]), fexp2(sc[mg][3][1]));
            uint w12 = pack_bf_trunc(fexp2(sc[mg][2][2]), fexp2(sc[mg][3][2]));
            uint w13 = pack_bf_trunc(fexp2(sc[mg][2][3]), fexp2(sc[mg][3][3]));
            bfly(w00, w02);
            bfly(w01, w03);
            bfly(w10, w12);
            bfly(w11, w13);
            union { uint u[4]; bf16x8 h; } u0, u1;
            u0.u[0] = w00; u0.u[1] = w10; u0.u[2] = w01; u0.u[3] = w11;
            u1.u[0] = w02; u1.u[1] = w12; u1.u[2] = w03; u1.u[3] = w13;
            ap[mg][0] = u0.h;
            ap[mg][1] = u1.h;
        }

        // PV + l via ones-MFMA; V fragment loaded once, used by both mg
        __builtin_amdgcn_s_setprio(1);
        #pragma unroll
        for (int nt = 0; nt < 4; nt++) {
            int d = nt * 16 + l16;
            bf16x8 bv0 = *(const bf16x8*)&Vs[d * 64 + ((quad ^ (d & 7)) << 3)];
            bf16x8 bv1 = *(const bf16x8*)&Vs[d * 64 + (((4 + quad) ^ (d & 7)) << 3)];
            #pragma unroll
            for (int mg = 0; mg < 2; mg++) {
                o[mg][nt] = __builtin_amdgcn_mfma_f32_16x16x32_bf16(ap[mg][0], bv0, o[mg][nt], 0, 0, 0);
                o[mg][nt] = __builtin_amdgcn_mfma_f32_16x16x32_bf16(ap[mg][1], bv1, o[mg][nt], 0, 0, 0);
            }
        }
        #pragma unroll
        for (int mg = 0; mg < 2; mg++) {
            lacc[mg] = __builtin_amdgcn_mfma_f32_16x16x32_bf16(ap[mg][0], b_ones, lacc[mg], 0, 0, 0);
            lacc[mg] = __builtin_amdgcn_mfma_f32_16x16x32_bf16(ap[mg][1], b_ones, lacc[mg], 0, 0, 0);
        }
        __builtin_amdgcn_s_setprio(0);

        // everyone done reading buf[cur]; tile t+1 loads drained by barrier
        __syncthreads();
        cur ^= 1;
    }

    // epilogue: per-wave, no cross-wave combine
    #pragma unroll
    for (int mg = 0; mg < 2; mg++) {
        #pragma unroll
        for (int r = 0; r < 4; r++) {
            float inv = 1.f / lacc[mg][r];
            int row = b * SEQ + qbase + mg * 16 + quad * 4 + r;
            size_t base = (size_t)row * HIDDEN + hoff + l16;
            #pragma unroll
            for (int nt = 0; nt < 4; nt++)
                attn[base + nt * 16] = f2bf(o[mg][nt][r] * inv);
        }
    }
}

// ---------------------------------------------------------------------------
// Fallback attention (no vtg workspace): barrier kernel staging K + Pi-V.
// ---------------------------------------------------------------------------
__global__ __launch_bounds__(512, 4)
void attn_mfma_fb_kernel(const ushort* __restrict__ qkvb,
                         ushort* __restrict__ attn)
{
    __shared__ __align__(16) ushort smem[34816];

    const int tid   = threadIdx.x;
    const int wave  = tid >> 6;
    const int wavel = wave & 3;
    const int kh    = wave >> 2;
    const int lane  = tid & 63;
    const int l16   = lane & 15;
    const int quad  = lane >> 4;

    const int qb = blockIdx.x & 15;
    const int bh = blockIdx.x >> 4;
    const int h  = bh & (NH - 1);
    const int b  = bh >> 4;

    const int qbase = qb * 128;
    const int hoff  = h * 64;

    ushort* KsH = smem + kh * 4096;
    ushort* VsH = smem + 8192 + kh * 4096;
    ushort* Psw = smem + 16384 + wave * 2304;

    bf16x8 a_q[2][2];
    #pragma unroll
    for (int mg = 0; mg < 2; mg++) {
        int qrow = b * SEQ + qbase + wavel * 32 + mg * 16 + l16;
        const ushort* qp = qkvb + (size_t)qrow * 3072 + hoff + quad * 8;
        a_q[mg][0] = *(const bf16x8*)qp;
        a_q[mg][1] = *(const bf16x8*)(qp + 32);
    }

    f32x4 o[2][4];
    f32x4 lacc[2];
    #pragma unroll
    for (int mg = 0; mg < 2; mg++) {
        lacc[mg] = (f32x4){0.f, 0.f, 0.f, 0.f};
        #pragma unroll
        for (int nt = 0; nt < 4; nt++) o[mg][nt] = (f32x4){0.f, 0.f, 0.f, 0.f};
    }

    bf16x8 b_ones;
    #pragma unroll
    for (int j = 0; j < 8; j++) b_ones[j] = (short)0x3f80;

    const ushort* kvb = qkvb + (size_t)b * SEQ * 3072;

    for (int t = 0; t < 16; t++) {
        const int k0 = t * 64;
        __syncthreads();
        {
            const int tl = tid & 255;
            #pragma unroll
            for (int i = 0; i < 2; i++) {
                int key = (tl >> 3) + 32 * i;
                int blk = tl & 7;
                const ushort* ksrc = kvb + (size_t)(kh * 1024 + k0 + key) * 3072 + 1024 + hoff + blk * 8;
                uint4 kv = *(const uint4*)ksrc;
                *(uint4*)&KsH[key * 64 + ((blk ^ (key & 7)) << 3)] = kv;
                uint4 vv = *(const uint4*)(ksrc + 1024);
                const ushort* vpp = (const ushort*)&vv;
                int pk_ = (key & 15) * 4 + (key >> 4);
                #pragma unroll
                for (int j = 0; j < 8; j++) {
                    int d = blk * 8 + j;
                    VsH[d * 64 + (((pk_ >> 3) ^ (d & 7)) << 3) + (pk_ & 7)] = vpp[j];
                }
            }
        }
        __syncthreads();

        f32x4 sc[2][4];
        #pragma unroll
        for (int nt = 0; nt < 4; nt++) {
            int key = nt * 16 + l16;
            bf16x8 bk0 = *(const bf16x8*)&KsH[key * 64 + ((quad ^ (key & 7)) << 3)];
            bf16x8 bk1 = *(const bf16x8*)&KsH[key * 64 + (((4 + quad) ^ (key & 7)) << 3)];
            #pragma unroll
            for (int mg = 0; mg < 2; mg++) {
                f32x4 a = (f32x4){0.f, 0.f, 0.f, 0.f};
                a = __builtin_amdgcn_mfma_f32_16x16x32_bf16(a_q[mg][0], bk0, a, 0, 0, 0);
                a = __builtin_amdgcn_mfma_f32_16x16x32_bf16(a_q[mg][1], bk1, a, 0, 0, 0);
                sc[mg][nt] = a;
            }
        }

        #pragma unroll
        for (int mg = 0; mg < 2; mg++) {
            #pragma unroll
            for (int r = 0; r < 4; r++) {
                int q = mg * 16 + quad * 4 + r;
                uint2 pk2;
                pk2.x = pack_bf_trunc(fexp2(sc[mg][0][r]), fexp2(sc[mg][1][r]));
                pk2.y = pack_bf_trunc(fexp2(sc[mg][2][r]), fexp2(sc[mg][3][r]));
                *(uint2*)&Psw[q * 72 + l16 * 4] = pk2;
            }
        }

        asm volatile("s_waitcnt lgkmcnt(0)" ::: "memory");
        bf16x8 a_p[2][2];
        #pragma unroll
        for (int mg = 0; mg < 2; mg++) {
            a_p[mg][0] = *(const bf16x8*)&Psw[(mg * 16 + l16) * 72 + quad * 8];
            a_p[mg][1] = *(const bf16x8*)&Psw[(mg * 16 + l16) * 72 + 32 + quad * 8];
        }

        #pragma unroll
        for (int nt = 0; nt < 4; nt++) {
            int d = nt * 16 + l16;
            bf16x8 bv0 = *(const bf16x8*)&VsH[d * 64 + ((quad ^ (d & 7)) << 3)];
            bf16x8 bv1 = *(const bf16x8*)&VsH[d * 64 + (((4 + quad) ^ (d & 7)) << 3)];
            #pragma unroll
            for (int mg = 0; mg < 2; mg++) {
                o[mg][nt] = __builtin_amdgcn_mfma_f32_16x16x32_bf16(a_p[mg][0], bv0, o[mg][nt], 0, 0, 0);
                o[mg][nt] = __builtin_amdgcn_mfma_f32_16x16x32_bf16(a_p[mg][1], bv1, o[mg][nt], 0, 0, 0);
            }
        }
        #pragma unroll
        for (int mg = 0; mg < 2; mg++) {
            lacc[mg] = __builtin_amdgcn_mfma_f32_16x16x32_bf16(a_p[mg][0], b_ones, lacc[mg], 0, 0, 0);
            lacc[mg] = __builtin_amdgcn_mfma_f32_16x16x32_bf16(a_p[mg][1], b_ones, lacc[mg], 0, 0, 0);
        }
    }

    __syncthreads();
    float* osc = (float*)smem;
    float* lsc = (float*)(smem + 16384);
    const int fo = wavel * 2048 + quad * 64 + l16 * 4;
    const int fl = wavel * 512 + quad * 64 + l16 * 4;
    if (kh == 1) {
        #pragma unroll
        for (int mg = 0; mg < 2; mg++) {
            #pragma unroll
            for (int nt = 0; nt < 4; nt++)
                *(f32x4*)&osc[fo + (mg * 4 + nt) * 256] = o[mg][nt];
            *(f32x4*)&lsc[fl + mg * 256] = lacc[mg];
        }
    }
    __syncthreads();
    if (kh == 0) {
        #pragma unroll
        for (int mg = 0; mg < 2; mg++) {
            #pragma unroll
            for (int nt = 0; nt < 4; nt++)
                o[mg][nt] += *(const f32x4*)&osc[fo + (mg * 4 + nt) * 256];
            lacc[mg] += *(const f32x4*)&lsc[fl + mg * 256];
        }
        #pragma unroll
        for (int mg = 0; mg < 2; mg++) {
            #pragma unroll
            for (int r = 0; r < 4; r++) {
                float inv = 1.f / lacc[mg][r];
                int row = b * SEQ + qbase + wavel * 32 + mg * 16 + quad * 4 + r;
                size_t base = (size_t)row * HIDDEN + hoff + l16;
                #pragma unroll
                for (int nt = 0; nt < 4; nt++)
                    attn[base + nt * 16] = f2bf(o[mg][nt][r] * inv);
            }
        }
    }
}

extern "C" void kernel_launch(void* const* d_in, const int* in_sizes, int n_in,
                              void* d_out, int out_size, void* d_ws, size_t ws_size,
                              hipStream_t stream) {
    const float* x    = (const float*)d_in[0];
    const float* Wqkv = (const float*)d_in[1];
    const float* bqkv = (const float*)d_in[2];
    const float* Wo   = (const float*)d_in[3];
    const float* bo   = (const float*)d_in[4];
    float* out = (float*)d_out;

    const int M = BATCH * SEQ;                   // 4096
    const size_t MB = 1024 * 1024;

    // workspace (48 MB):
    //   [0,24) qkvb | [24,32) attn (xb overlaps: prep/GEMM1 only)
    //   [32,38) Wt (prep/GEMM1) | [38,40) WoT (prep->GEMM3) | [40,48) vtg
    char* ws = (char*)d_ws;
    ushort* qkvb = (ushort*)ws;
    ushort* attn = (ushort*)(ws + 24 * MB);
    ushort* xb   = (ushort*)(ws + 24 * MB);
    ushort* Wt   = (ushort*)(ws + 32 * MB);
    ushort* WoT  = (ushort*)(ws + 38 * MB);
    ushort* vtg  = (ushort*)(ws + 40 * MB);
    const int use_vtg = (ws_size >= 48 * MB) ? 1 : 0;

    const float qscale = 0.125f * 1.44269504088896f;   // fold log2e -> exp2 softmax

    // 0) fused preps (x->bf16, Wqkv transpose, Wo transpose)
    prep_kernel<<<8192, 256, 0, stream>>>(x, Wqkv, Wo, xb, Wt, WoT);

    // 1) qkv = (x @ Wqkv + bqkv) -> bf16; V written transposed to vtg when able
    {
        dim3 grid((3 * HIDDEN) / 128, M / 128);
        gemm_mfma_bf16_kernel<<<grid, 256, 0, stream>>>(xb, Wt, bqkv, qkvb,
                                                        3 * HIDDEN, HIDDEN, qscale,
                                                        vtg, use_vtg);
    }

    // 2) flash attention -> attn bf16
    if (use_vtg) {
        attn_mfma_v12_kernel<<<BATCH * NH * (SEQ / 128), 256, 0, stream>>>(
            qkvb, vtg, attn);
    } else {
        attn_mfma_fb_kernel<<<BATCH * NH * (SEQ / 128), 512, 0, stream>>>(
            qkvb, attn);
    }

    // 3) out = attn @ Wo + bo (single-pass bf16 MFMA)
    {
        dim3 grid(HIDDEN / 64, M / 128);
        gemm_out_kernel<<<grid, 256, 0, stream>>>(attn, WoT, bo, out);
    }
}